// Round 8
// baseline (418.680 us; speedup 1.0000x reference)
//
#include <hip/hip_runtime.h>
#include <math.h>

static constexpr int Bsz = 4, Tn = 1024, Dn = 512, Hn = 8, Fn = 2048, Kw = 31, Dk = 64;
static constexpr size_t N_OUT  = (size_t)Bsz * Tn * Dn;   // 2,097,152
static constexpr size_t N_POSK = (size_t)Tn * Tn * Dk;    // 67,108,864
static constexpr size_t N_MASK = (size_t)Bsz * Tn * Tn;   // 4,194,304

typedef __attribute__((ext_vector_type(8))) short bhalf8;  // 8 bf16 (4 VGPR)
typedef __attribute__((ext_vector_type(4))) float f4;      // MFMA C/D

__device__ __forceinline__ ushort f2b(float f) {
  uint b = __float_as_uint(f);
  uint r = (b + 0x7FFFu + ((b >> 16) & 1u)) >> 16;
  return (ushort)r;
}
__device__ __forceinline__ float b2f(ushort u) {
  return __uint_as_float((uint)u << 16);
}

// async global->LDS, 16 B per lane
typedef const __attribute__((address_space(1))) unsigned int* gp1_t;
typedef __attribute__((address_space(3))) unsigned int* lp3_t;
__device__ __forceinline__ void gload16(const void* g, void* l) {
  __builtin_amdgcn_global_load_lds((gp1_t)g, (lp3_t)l, 16, 0, 0);
}

// ---------------------------------------------------------------------------
// LayerNorm; BF=1 -> bf16 output, BF=0 -> fp32 output. GLU on fp32 path.
// ---------------------------------------------------------------------------
template <int GLU, int BF>
__global__ __launch_bounds__(256) void ln_kernel(
    const float* __restrict__ x, const float* __restrict__ g,
    const float* __restrict__ b, float* __restrict__ yf,
    ushort* __restrict__ yb, const float* __restrict__ pw1w,
    const float* __restrict__ pw1b) {
  const int row = blockIdx.x;
  const float* xr = x + (size_t)row * Dn;
  const int tid = threadIdx.x, wid = tid >> 6, lane = tid & 63;

  __shared__ float red[4];
  __shared__ float bc[2];

  float v0 = xr[tid], v1 = xr[tid + 256];
  float s = v0 + v1;
#pragma unroll
  for (int off = 32; off; off >>= 1) s += __shfl_xor(s, off);
  if (lane == 0) red[wid] = s;
  __syncthreads();
  if (tid == 0) bc[0] = (red[0] + red[1] + red[2] + red[3]) * (1.0f / Dn);
  __syncthreads();
  const float m = bc[0];
  const float d0 = v0 - m, d1 = v1 - m;
  float s2 = d0 * d0 + d1 * d1;
#pragma unroll
  for (int off = 32; off; off >>= 1) s2 += __shfl_xor(s2, off);
  if (lane == 0) red[wid] = s2;
  __syncthreads();
  if (tid == 0)
    bc[1] = rsqrtf((red[0] + red[1] + red[2] + red[3]) * (1.0f / Dn) + 1e-5f);
  __syncthreads();
  const float r = bc[1];

  float o0 = d0 * r * g[tid] + b[tid];
  float o1 = d1 * r * g[tid + 256] + b[tid + 256];
  if (GLU) {
    const float w0 = pw1w[0], w1 = pw1w[1], c0 = pw1b[0], c1 = pw1b[1];
    o0 = (w0 * o0 + c0) * (1.0f / (1.0f + expf(-(w1 * o0 + c1))));
    o1 = (w0 * o1 + c0) * (1.0f / (1.0f + expf(-(w1 * o1 + c1))));
  }
  if (BF) {
    yb[(size_t)row * Dn + tid] = f2b(o0);
    yb[(size_t)row * Dn + tid + 256] = f2b(o1);
  } else {
    yf[(size_t)row * Dn + tid] = o0;
    yf[(size_t)row * Dn + tid + 256] = o1;
  }
}

// ---------------------------------------------------------------------------
// Weight convert+transpose: W (K x N fp32, row-major) -> Wt (N x K bf16)
// ---------------------------------------------------------------------------
__global__ __launch_bounds__(256) void wcvt_kernel(const float* __restrict__ W,
                                                   ushort* __restrict__ Wt,
                                                   int K, int N) {
  __shared__ float tile[32][33];
  const int n0 = blockIdx.x * 32, k0 = blockIdx.y * 32;
  const int tx = threadIdx.x & 31, ty = threadIdx.x >> 5;
#pragma unroll
  for (int i = 0; i < 4; ++i) {
    int k = ty + i * 8;
    tile[k][tx] = W[(size_t)(k0 + k) * N + n0 + tx];
  }
  __syncthreads();
#pragma unroll
  for (int i = 0; i < 4; ++i) {
    int r = ty + i * 8;
    Wt[(size_t)(n0 + r) * K + k0 + tx] = f2b(tile[tx][r]);
  }
}

// ---------------------------------------------------------------------------
// bf16 MFMA GEMM (NT), tile BM x BN, 4 waves (2x2), wave tile BM/2 x BN/2.
// MODE 0: relu -> bf16 Cb     MODE 1: C = res + 0.5*v (fp32)
// MODE 3: C = res + v (fp32)  MODE 4: Cb = bf16(v)
// ---------------------------------------------------------------------------
template <int MODE, int BM, int BN>
__global__ __launch_bounds__(256) void mgemm_kernel(
    const ushort* __restrict__ A, const ushort* __restrict__ Bt,
    const float* __restrict__ bias, const float* __restrict__ res,
    float* __restrict__ C, ushort* __restrict__ Cb, int M, int N, int K) {
  constexpr int NFM = BM / 32;  // frags per wave, M dim
  constexpr int NFN = BN / 32;
  __shared__ ushort As[BM * 64];
  __shared__ ushort Bs[BN * 64];
  const int bm = blockIdx.y * BM, bn = blockIdx.x * BN;
  const int tid = threadIdx.x;
  const int wid = tid >> 6, l = tid & 63;
  const int wm = wid >> 1, wn = wid & 1;
  const int l16 = l & 15, lhi = l >> 4;

  f4 acc[NFM][NFN] = {};

  for (int k0 = 0; k0 < K; k0 += 64) {
#pragma unroll
    for (int i = 0; i < BM * 8 / 256; ++i) {
      int slot = tid + i * 256;
      int row = slot >> 3, c8 = slot & 7;
      gload16(A + (size_t)(bm + row) * K + k0 + c8 * 8, &As[slot * 8]);
    }
#pragma unroll
    for (int i = 0; i < BN * 8 / 256; ++i) {
      int slot = tid + i * 256;
      int row = slot >> 3, c8 = slot & 7;
      gload16(Bt + (size_t)(bn + row) * K + k0 + c8 * 8, &Bs[slot * 8]);
    }
    __syncthreads();
#pragma unroll
    for (int ks = 0; ks < 2; ++ks) {
      bhalf8 a[NFM], b[NFN];
#pragma unroll
      for (int mi = 0; mi < NFM; ++mi)
        a[mi] = *(const bhalf8*)&As[(wm * (BM / 2) + mi * 16 + l16) * 64 +
                                    ks * 32 + lhi * 8];
#pragma unroll
      for (int ni = 0; ni < NFN; ++ni)
        b[ni] = *(const bhalf8*)&Bs[(wn * (BN / 2) + ni * 16 + l16) * 64 +
                                    ks * 32 + lhi * 8];
#pragma unroll
      for (int mi = 0; mi < NFM; ++mi)
#pragma unroll
        for (int ni = 0; ni < NFN; ++ni)
          acc[mi][ni] = __builtin_amdgcn_mfma_f32_16x16x32_bf16(
              a[mi], b[ni], acc[mi][ni], 0, 0, 0);
    }
    __syncthreads();
  }

#pragma unroll
  for (int mi = 0; mi < NFM; ++mi) {
#pragma unroll
    for (int ni = 0; ni < NFN; ++ni) {
      const int col = bn + wn * (BN / 2) + ni * 16 + l16;
      const float bv = bias[col];
#pragma unroll
      for (int r = 0; r < 4; ++r) {
        const int row = bm + wm * (BM / 2) + mi * 16 + lhi * 4 + r;
        float v = acc[mi][ni][r] + bv;
        const size_t off = (size_t)row * N + col;
        if (MODE == 0) {
          Cb[off] = f2b(fmaxf(v, 0.0f));
        } else if (MODE == 4) {
          Cb[off] = f2b(v);
        } else {
          if (MODE == 1) v = res[off] + 0.5f * v;
          if (MODE == 3) v = res[off] + v;
          C[off] = v;
        }
      }
    }
  }
}

// ---------------------------------------------------------------------------
// bmm: Sc16[bh][t][s] = bf16( q . pos_k[t,s,:] ); PASS=1 also writes the
// pos_k passthrough copy. Output goes through LDS for coalesced stores.
// ---------------------------------------------------------------------------
template <int PASS>
__global__ __launch_bounds__(256) void bmm_kernel(const ushort* __restrict__ qbf,
                                                  const float* __restrict__ pk,
                                                  ushort* __restrict__ Sc16,
                                                  float* __restrict__ pkout) {
  const int s0 = blockIdx.x * 256;
  const int t = blockIdx.y;
  const int tid = threadIdx.x, wid = tid >> 6, l = tid & 63;
  const int l16 = l & 15, lhi = l >> 4;

  __shared__ ushort Qs[32 * 64];
  __shared__ ushort Ps[256 * 64];  // pos_k staging; reused for output transpose

  {
    int row = tid >> 3, c8 = tid & 7;
    int bq = row >> 3, hq = row & 7;
    *(uint4*)&Qs[row * 64 + c8 * 8] =
        *(const uint4*)(qbf + ((size_t)(bq * Tn + t)) * Dn + hq * 64 + c8 * 8);
  }
#pragma unroll
  for (int i = 0; i < 16; ++i) {
    int slot = tid + i * 256;
    int sr = slot >> 4, c4 = slot & 15;
    const size_t goff = ((size_t)t * Tn + s0 + sr) * Dk + c4 * 4;
    const float4 p = *(const float4*)(pk + goff);
    if (PASS) *(float4*)(pkout + goff) = p;
    ushort4 u;
    u.x = f2b(p.x);
    u.y = f2b(p.y);
    u.z = f2b(p.z);
    u.w = f2b(p.w);
    *(ushort4*)&Ps[sr * 64 + c4 * 4] = u;
  }
  __syncthreads();

  f4 acc[2][4] = {};
#pragma unroll
  for (int ks = 0; ks < 2; ++ks) {
    bhalf8 a[2], b[4];
#pragma unroll
    for (int mi = 0; mi < 2; ++mi)
      a[mi] = *(const bhalf8*)&Qs[(mi * 16 + l16) * 64 + ks * 32 + lhi * 8];
#pragma unroll
    for (int ni = 0; ni < 4; ++ni)
      b[ni] = *(const bhalf8*)&Ps[(wid * 64 + ni * 16 + l16) * 64 + ks * 32 +
                                  lhi * 8];
#pragma unroll
    for (int mi = 0; mi < 2; ++mi)
#pragma unroll
      for (int ni = 0; ni < 4; ++ni)
        acc[mi][ni] = __builtin_amdgcn_mfma_f32_16x16x32_bf16(
            a[mi], b[ni], acc[mi][ni], 0, 0, 0);
  }

  __syncthreads();  // all waves done reading Ps (pos_k staging)
  // scatter acc into Ps as [32 bh][256 s] (2 B/lane consecutive -> conflict-free)
#pragma unroll
  for (int mi = 0; mi < 2; ++mi)
#pragma unroll
    for (int ni = 0; ni < 4; ++ni)
#pragma unroll
      for (int r = 0; r < 4; ++r) {
        const int bh = mi * 16 + lhi * 4 + r;
        const int sl = wid * 64 + ni * 16 + l16;
        Ps[bh * 256 + sl] = f2b(acc[mi][ni][r]);
      }
  __syncthreads();
  // coalesced uint4 writes: 512 B per bh row
#pragma unroll
  for (int i = 0; i < 4; ++i) {
    int idx = tid + i * 256;
    int bh = idx >> 5, sc = (idx & 31) * 8;
    *(uint4*)&Sc16[((size_t)bh * Tn + t) * Tn + s0 + sc] =
        *(const uint4*)&Ps[bh * 256 + sc];
  }
}

// ---------------------------------------------------------------------------
// fattn: flash attention. Per block: 128 t rows x one bh. Iterate 128-s tiles:
// acc = Bm (from Sc16, C-layout global u16 loads) + Q.K^T (MFMA); *scale;
// masked via packed bits; online softmax (regs); P->LDS (XOR swizzle); PV.
// FIX vs R7: K and V tiles stage all 128 rows (were half-staged).
// ---------------------------------------------------------------------------
__global__ __launch_bounds__(256) void fattn_kernel(
    const ushort* __restrict__ qbf, const ushort* __restrict__ kbf,
    const ushort* __restrict__ vbf, const ushort* __restrict__ Sc16,
    const uint* __restrict__ mbits, ushort* __restrict__ ctxb) {
  const int bh = blockIdx.y;
  const int b = bh >> 3, h = bh & 7;
  const int t0 = blockIdx.x * 128;
  const int tid = threadIdx.x;
  const int wid = tid >> 6, l = tid & 63;
  const int l16 = l & 15, lhi = l >> 4;

  __shared__ ushort KV[8448];       // K [128][64] (8192) / V^T [64][132] (8448)
  __shared__ ushort Ps[128 * 128];  // P (swizzled); also Q staging

  // Q fragments -> registers (staged via Ps)
  bhalf8 qa[2][2];
  {
#pragma unroll
    for (int i = 0; i < 4; ++i) {
      int slot = tid + i * 256;
      int row = slot >> 3, c8 = slot & 7;
      gload16(qbf + ((size_t)(b * Tn + t0 + row)) * Dn + h * 64 + c8 * 8,
              &Ps[slot * 8]);
    }
    __syncthreads();
#pragma unroll
    for (int mi = 0; mi < 2; ++mi)
#pragma unroll
      for (int ks = 0; ks < 2; ++ks)
        qa[mi][ks] = *(const bhalf8*)&Ps[(wid * 32 + mi * 16 + l16) * 64 +
                                         ks * 32 + lhi * 8];
    __syncthreads();
  }

  f4 oacc[2][4] = {};
  float mrow[2][4], lrow[2][4];
#pragma unroll
  for (int mi = 0; mi < 2; ++mi)
#pragma unroll
    for (int r = 0; r < 4; ++r) {
      mrow[mi][r] = -3.0e38f;
      lrow[mi][r] = 0.0f;
    }

  const float scale = 0.125f;
  for (int s0 = 0; s0 < Tn; s0 += 128) {
    // stage K [128 s][64 dk]  (full tile)
#pragma unroll
    for (int i = 0; i < 4; ++i) {
      int slot = tid + i * 256;
      int row = slot >> 3, c8 = slot & 7;
      gload16(kbf + ((size_t)(b * Tn + s0 + row)) * Dn + h * 64 + c8 * 8,
              &KV[slot * 8]);
    }
    // acc init = Bm (C-layout direct global loads; Sc16 is L3-resident)
    f4 accs[2][8];
#pragma unroll
    for (int mi = 0; mi < 2; ++mi)
#pragma unroll
      for (int r = 0; r < 4; ++r) {
        const int trow = t0 + wid * 32 + mi * 16 + lhi * 4 + r;
        const ushort* src = Sc16 + ((size_t)bh * Tn + trow) * Tn + s0;
#pragma unroll
        for (int ni = 0; ni < 8; ++ni) accs[mi][ni][r] = b2f(src[ni * 16 + l16]);
      }
    __syncthreads();  // K visible

    // QK^T
#pragma unroll
    for (int ks = 0; ks < 2; ++ks) {
      bhalf8 bb[8];
#pragma unroll
      for (int ni = 0; ni < 8; ++ni)
        bb[ni] = *(const bhalf8*)&KV[(ni * 16 + l16) * 64 + ks * 32 + lhi * 8];
#pragma unroll
      for (int mi = 0; mi < 2; ++mi)
#pragma unroll
        for (int ni = 0; ni < 8; ++ni)
          accs[mi][ni] = __builtin_amdgcn_mfma_f32_16x16x32_bf16(
              qa[mi][ks], bb[ni], accs[mi][ni], 0, 0, 0);
    }

    // online softmax (in regs) + P write (swizzled)
#pragma unroll
    for (int mi = 0; mi < 2; ++mi)
#pragma unroll
      for (int r = 0; r < 4; ++r) {
        const int trow = t0 + wid * 32 + mi * 16 + lhi * 4 + r;
        const uint* mw = mbits + ((size_t)b * Tn + trow) * 32 + (s0 >> 5);
        const uint w[4] = {mw[0], mw[1], mw[2], mw[3]};
        float p[8];
        float rm = -3.0e38f;
#pragma unroll
        for (int ni = 0; ni < 8; ++ni) {
          float v = accs[mi][ni][r] * scale;
          const uint bit = (w[ni >> 1] >> ((ni & 1) * 16 + l16)) & 1u;
          v = bit ? v : -3.0e38f;
          p[ni] = v;
          rm = fmaxf(rm, v);
        }
#pragma unroll
        for (int off = 8; off; off >>= 1) rm = fmaxf(rm, __shfl_xor(rm, off));
        const float mnew = fmaxf(mrow[mi][r], rm);
        const float sold = __expf(mrow[mi][r] - mnew);
        mrow[mi][r] = mnew;
        float rs = 0.0f;
#pragma unroll
        for (int ni = 0; ni < 8; ++ni) {
          const float e = __expf(p[ni] - mnew);
          rs += e;
          p[ni] = e;
        }
#pragma unroll
        for (int off = 8; off; off >>= 1) rs += __shfl_xor(rs, off);
        lrow[mi][r] = lrow[mi][r] * sold + rs;
#pragma unroll
        for (int ni = 0; ni < 4; ++ni) oacc[mi][ni][r] *= sold;
        const int lr = wid * 32 + mi * 16 + lhi * 4 + r;
#pragma unroll
        for (int ni = 0; ni < 8; ++ni) {
          const int byte =
              (lr * 256 + (ni * 16 + l16) * 2) ^ ((lr & 7) << 4);
          *(ushort*)((char*)Ps + byte) = f2b(p[ni]);
        }
      }
    __syncthreads();  // QK done reading KV; P written

    // stage V^T [64 d][132 stride], all 128 s rows
#pragma unroll
    for (int i = 0; i < 4; ++i) {
      int slot = tid + i * 256;
      int sr = slot >> 3, c8 = slot & 7;  // sr 0..127
      const uint4 raw = *(const uint4*)(
          vbf + ((size_t)(b * Tn + s0 + sr)) * Dn + h * 64 + c8 * 8);
      const ushort* e = (const ushort*)&raw;
#pragma unroll
      for (int j = 0; j < 8; ++j) KV[(c8 * 8 + j) * 132 + sr] = e[j];
    }
    __syncthreads();  // V^T + P visible

    // PV
#pragma unroll
    for (int ks = 0; ks < 4; ++ks) {
      bhalf8 a[2], bb[4];
#pragma unroll
      for (int mi = 0; mi < 2; ++mi) {
        const int lr = wid * 32 + mi * 16 + l16;
        const int byte = (lr * 256 + ks * 64 + lhi * 16) ^ ((lr & 7) << 4);
        a[mi] = *(const bhalf8*)((char*)Ps + byte);
      }
#pragma unroll
      for (int ni = 0; ni < 4; ++ni)
        bb[ni] = *(const bhalf8*)&KV[(ni * 16 + l16) * 132 + ks * 32 + lhi * 8];
#pragma unroll
      for (int mi = 0; mi < 2; ++mi)
#pragma unroll
        for (int ni = 0; ni < 4; ++ni)
          oacc[mi][ni] = __builtin_amdgcn_mfma_f32_16x16x32_bf16(
              a[mi], bb[ni], oacc[mi][ni], 0, 0, 0);
    }
    __syncthreads();  // protect KV/Ps for next iter
  }

#pragma unroll
  for (int mi = 0; mi < 2; ++mi)
#pragma unroll
    for (int r = 0; r < 4; ++r) {
      const float inv = (mrow[mi][r] <= -1.0e37f)
                            ? 0.0f
                            : 1.0f / fmaxf(lrow[mi][r], 1e-30f);
      const int t = t0 + wid * 32 + mi * 16 + lhi * 4 + r;
#pragma unroll
      for (int ni = 0; ni < 4; ++ni) {
        const int d = ni * 16 + l16;
        ctxb[((size_t)(b * Tn + t)) * Dn + h * 64 + d] =
            f2b(oacc[mi][ni][r] * inv);
      }
    }
}

// ---------------------------------------------------------------------------
// conv2: depthwise conv1d (K=31) + ReLU + pw2 + residual; register window.
// ---------------------------------------------------------------------------
__global__ __launch_bounds__(256) void conv2_kernel(
    const float* __restrict__ y, const float* __restrict__ dww,
    const float* __restrict__ dwb, const float* __restrict__ pw2w,
    const float* __restrict__ pw2b, float* __restrict__ x) {
  const int b = blockIdx.z;
  const int d0 = blockIdx.y * 256;
  const int t0 = blockIdx.x * 16;
  const int tid = threadIdx.x;
  const int d = d0 + tid;

  __shared__ float wlds[256 * Kw];
#pragma unroll
  for (int i = 0; i < Kw; ++i)
    wlds[i * 256 + tid] = dww[(size_t)d0 * Kw + i * 256 + tid];
  __syncthreads();

  float w[Kw];
#pragma unroll
  for (int k = 0; k < Kw; ++k) w[k] = wlds[tid * Kw + k];

  float v[46];
#pragma unroll
  for (int i = 0; i < 46; ++i) {
    int t = t0 - 15 + i;
    v[i] = (t >= 0 && t < Tn) ? y[((size_t)b * Tn + t) * Dn + d] : 0.0f;
  }

  const float bias = dwb[d], w2 = pw2w[0], c2 = pw2b[0];
#pragma unroll
  for (int j = 0; j < 16; ++j) {
    float acc = bias;
#pragma unroll
    for (int k = 0; k < Kw; ++k) acc += w[k] * v[j + k];
    acc = fmaxf(acc, 0.0f);
    const size_t idx = ((size_t)b * Tn + t0 + j) * Dn + d;
    x[idx] = x[idx] + w2 * acc + c2;
  }
}

// ---------------------------------------------------------------------------
// maskcvt: int32 mask -> fp32 passthrough output AND packed bits (1 bit/s).
// ---------------------------------------------------------------------------
__global__ __launch_bounds__(256) void maskcvt_kernel(
    const int* __restrict__ in, float* __restrict__ outf,
    uint* __restrict__ mbits) {
  const size_t idx = (size_t)blockIdx.x * 256 + threadIdx.x;
  const size_t base = idx * 32;
  uint bits = 0;
#pragma unroll
  for (int j = 0; j < 8; ++j) {
    const int4 v = *(const int4*)(in + base + j * 4);
    float4 f;
    f.x = (float)v.x;
    f.y = (float)v.y;
    f.z = (float)v.z;
    f.w = (float)v.w;
    *(float4*)(outf + base + j * 4) = f;
    bits |= (v.x != 0 ? 1u : 0u) << (j * 4 + 0);
    bits |= (v.y != 0 ? 1u : 0u) << (j * 4 + 1);
    bits |= (v.z != 0 ? 1u : 0u) << (j * 4 + 2);
    bits |= (v.w != 0 ? 1u : 0u) << (j * 4 + 3);
  }
  mbits[idx] = bits;
}

// ---------------------------------------------------------------------------
extern "C" void kernel_launch(void* const* d_in, const int* in_sizes, int n_in,
                              void* d_out, int out_size, void* d_ws,
                              size_t ws_size, hipStream_t stream) {
  const float* x = (const float*)d_in[0];
  const float* pos_k = (const float*)d_in[1];
  const int* mask = (const int*)d_in[2];
  const float* fi_g = (const float*)d_in[3];
  const float* fi_b = (const float*)d_in[4];
  const float* fi_w1 = (const float*)d_in[5];
  const float* fi_b1 = (const float*)d_in[6];
  const float* fi_w2 = (const float*)d_in[7];
  const float* fi_b2 = (const float*)d_in[8];
  const float* at_g = (const float*)d_in[9];
  const float* at_b = (const float*)d_in[10];
  const float* wq = (const float*)d_in[11];
  const float* bq = (const float*)d_in[12];
  const float* wk = (const float*)d_in[13];
  const float* bk = (const float*)d_in[14];
  const float* wv = (const float*)d_in[15];
  const float* bv = (const float*)d_in[16];
  const float* wo = (const float*)d_in[17];
  const float* bo = (const float*)d_in[18];
  const float* cv_g = (const float*)d_in[19];
  const float* cv_b = (const float*)d_in[20];
  const float* pw1w = (const float*)d_in[21];
  const float* pw1b = (const float*)d_in[22];
  const float* dww = (const float*)d_in[23];
  const float* dwb = (const float*)d_in[24];
  const float* pw2w = (const float*)d_in[25];
  const float* pw2b = (const float*)d_in[26];
  const float* fo_g = (const float*)d_in[27];
  const float* fo_b = (const float*)d_in[28];
  const float* fo_w1 = (const float*)d_in[29];
  const float* fo_b1 = (const float*)d_in[30];
  const float* fo_w2 = (const float*)d_in[31];
  const float* fo_b2 = (const float*)d_in[32];
  const float* fl_g = (const float*)d_in[33];
  const float* fl_b = (const float*)d_in[34];

  float* out = (float*)d_out;

  // ws front: xcur | y | mbits (always; ~34.6 MB)
  float* xcur = (float*)d_ws;
  float* y = xcur + N_OUT;
  uint* mbits = (uint*)(y + N_OUT);  // N_MASK/32 uints = 512 KB

  // big scratch: prefer ws (enables fused pos_k passthrough); else out region
  const size_t NEED = (size_t)206 << 20;
  const bool fused = ws_size >= NEED;
  char* sp = fused ? (char*)(mbits + N_MASK / 32) : (char*)(out + N_OUT);
  auto alloc16 = [&](size_t elems) {
    ushort* p = (ushort*)sp;
    sp += ((elems * 2 + 255) & ~(size_t)255);
    return p;
  };
  ushort* Sc16 = alloc16((size_t)32 * Tn * Tn);  // 67 MB
  ushort* wt_fi1 = alloc16((size_t)Fn * Dn);
  ushort* wt_fi2 = alloc16((size_t)Dn * Fn);
  ushort* wt_q = alloc16((size_t)Dn * Dn);
  ushort* wt_k = alloc16((size_t)Dn * Dn);
  ushort* wt_v = alloc16((size_t)Dn * Dn);
  ushort* wt_o = alloc16((size_t)Dn * Dn);
  ushort* wt_fo1 = alloc16((size_t)Fn * Dn);
  ushort* wt_fo2 = alloc16((size_t)Dn * Fn);
  ushort* ybf = alloc16(N_OUT);
  ushort* hbf = alloc16((size_t)Bsz * Tn * Fn);
  ushort* ctxbf = alloc16(N_OUT);
  ushort* qbf = alloc16(N_OUT);
  ushort* kbf = alloc16(N_OUT);
  ushort* vbf = alloc16(N_OUT);

  const int M = Bsz * Tn;  // 4096
  const dim3 blk256(256);
  const dim3 grid_rows(M);
  const dim3 gF(Fn / 128, M / 128);     // 128x128, N=2048: 512 blocks
  const dim3 gD64(Dn / 64, M / 64);     // 64x64,  N=512: 512 blocks
  const dim3 gRect(Dn / 64, M / 128);   // 128x64, N=512: 256 blocks

  hipMemcpyAsync(xcur, x, N_OUT * sizeof(float), hipMemcpyDeviceToDevice,
                 stream);

  // mask passthrough + bit-pack (early; flash needs mbits)
  maskcvt_kernel<<<dim3(N_MASK / 32 / 256), blk256, 0, stream>>>(
      mask, out + N_OUT + N_POSK, mbits);

  // weight conversions (fp32 KxN -> bf16 NxK)
  wcvt_kernel<<<dim3(Fn / 32, Dn / 32), blk256, 0, stream>>>(fi_w1, wt_fi1, Dn, Fn);
  wcvt_kernel<<<dim3(Dn / 32, Fn / 32), blk256, 0, stream>>>(fi_w2, wt_fi2, Fn, Dn);
  wcvt_kernel<<<dim3(Dn / 32, Dn / 32), blk256, 0, stream>>>(wq, wt_q, Dn, Dn);
  wcvt_kernel<<<dim3(Dn / 32, Dn / 32), blk256, 0, stream>>>(wk, wt_k, Dn, Dn);
  wcvt_kernel<<<dim3(Dn / 32, Dn / 32), blk256, 0, stream>>>(wv, wt_v, Dn, Dn);
  wcvt_kernel<<<dim3(Dn / 32, Dn / 32), blk256, 0, stream>>>(wo, wt_o, Dn, Dn);
  wcvt_kernel<<<dim3(Fn / 32, Dn / 32), blk256, 0, stream>>>(fo_w1, wt_fo1, Dn, Fn);
  wcvt_kernel<<<dim3(Dn / 32, Fn / 32), blk256, 0, stream>>>(fo_w2, wt_fo2, Fn, Dn);

  // macaron FFN-in
  ln_kernel<0, 1><<<grid_rows, blk256, 0, stream>>>(xcur, fi_g, fi_b, nullptr,
                                                    ybf, nullptr, nullptr);
  mgemm_kernel<0, 128, 128><<<gF, blk256, 0, stream>>>(
      ybf, wt_fi1, fi_b1, nullptr, nullptr, hbf, M, Fn, Dn);
  mgemm_kernel<1, 128, 64><<<gRect, blk256, 0, stream>>>(
      hbf, wt_fi2, fi_b2, xcur, xcur, nullptr, M, Dn, Fn);

  // attention projections (bf16 outputs)
  ln_kernel<0, 1><<<grid_rows, blk256, 0, stream>>>(xcur, at_g, at_b, nullptr,
                                                    ybf, nullptr, nullptr);
  mgemm_kernel<4, 64, 64><<<gD64, blk256, 0, stream>>>(
      ybf, wt_q, bq, nullptr, nullptr, qbf, M, Dn, Dn);
  mgemm_kernel<4, 64, 64><<<gD64, blk256, 0, stream>>>(
      ybf, wt_k, bk, nullptr, nullptr, kbf, M, Dn, Dn);
  mgemm_kernel<4, 64, 64><<<gD64, blk256, 0, stream>>>(
      ybf, wt_v, bv, nullptr, nullptr, vbf, M, Dn, Dn);

  if (fused)
    bmm_kernel<1><<<dim3(4, Tn), blk256, 0, stream>>>(qbf, pos_k, Sc16,
                                                      out + N_OUT);
  else
    bmm_kernel<0><<<dim3(4, Tn), blk256, 0, stream>>>(qbf, pos_k, Sc16,
                                                      nullptr);

  fattn_kernel<<<dim3(Tn / 128, 32), blk256, 0, stream>>>(qbf, kbf, vbf, Sc16,
                                                          mbits, ctxbf);

  mgemm_kernel<3, 64, 64><<<gD64, blk256, 0, stream>>>(
      ctxbf, wt_o, bo, xcur, xcur, nullptr, M, Dn, Dn);

  // conv module
  ln_kernel<1, 0><<<grid_rows, blk256, 0, stream>>>(xcur, cv_g, cv_b, y,
                                                    nullptr, pw1w, pw1b);
  conv2_kernel<<<dim3(Tn / 16, 2, Bsz), blk256, 0, stream>>>(y, dww, dwb, pw2w,
                                                             pw2b, xcur);

  // macaron FFN-out
  ln_kernel<0, 1><<<grid_rows, blk256, 0, stream>>>(xcur, fo_g, fo_b, nullptr,
                                                    ybf, nullptr, nullptr);
  mgemm_kernel<0, 128, 128><<<gF, blk256, 0, stream>>>(
      ybf, wt_fo1, fo_b1, nullptr, nullptr, hbf, M, Fn, Dn);
  mgemm_kernel<1, 128, 64><<<gRect, blk256, 0, stream>>>(
      hbf, wt_fo2, fo_b2, xcur, xcur, nullptr, M, Dn, Fn);

  // final LN -> d_out[0]
  ln_kernel<0, 0><<<grid_rows, blk256, 0, stream>>>(xcur, fl_g, fl_b, out,
                                                    nullptr, nullptr, nullptr);

  // pos_k passthrough (only if not fused into bmm)
  if (!fused)
    hipMemcpyAsync(out + N_OUT, pos_k, N_POSK * sizeof(float),
                   hipMemcpyDeviceToDevice, stream);
}

// Round 9
// 389.388 us; speedup vs baseline: 1.0752x; 1.0752x over previous
//
#include <hip/hip_runtime.h>
#include <math.h>

static constexpr int Bsz = 4, Tn = 1024, Dn = 512, Hn = 8, Fn = 2048, Kw = 31, Dk = 64;
static constexpr int QS = 3 * Dn;  // 1536, qkv row stride
static constexpr size_t N_OUT  = (size_t)Bsz * Tn * Dn;   // 2,097,152
static constexpr size_t N_POSK = (size_t)Tn * Tn * Dk;    // 67,108,864
static constexpr size_t N_MASK = (size_t)Bsz * Tn * Tn;   // 4,194,304

typedef __attribute__((ext_vector_type(8))) short bhalf8;  // 8 bf16 (4 VGPR)
typedef __attribute__((ext_vector_type(4))) float f4;      // MFMA C/D

__device__ __forceinline__ ushort f2b(float f) {
  uint b = __float_as_uint(f);
  uint r = (b + 0x7FFFu + ((b >> 16) & 1u)) >> 16;
  return (ushort)r;
}
__device__ __forceinline__ float b2f(ushort u) {
  return __uint_as_float((uint)u << 16);
}

// async global->LDS, 16 B per lane
typedef const __attribute__((address_space(1))) unsigned int* gp1_t;
typedef __attribute__((address_space(3))) unsigned int* lp3_t;
__device__ __forceinline__ void gload16(const void* g, void* l) {
  __builtin_amdgcn_global_load_lds((gp1_t)g, (lp3_t)l, 16, 0, 0);
}

// ---------------------------------------------------------------------------
// LayerNorm; BF=1 -> bf16 output, BF=0 -> fp32 output. GLU on fp32 path.
// ---------------------------------------------------------------------------
template <int GLU, int BF>
__global__ __launch_bounds__(256) void ln_kernel(
    const float* __restrict__ x, const float* __restrict__ g,
    const float* __restrict__ b, float* __restrict__ yf,
    ushort* __restrict__ yb, const float* __restrict__ pw1w,
    const float* __restrict__ pw1b) {
  const int row = blockIdx.x;
  const float* xr = x + (size_t)row * Dn;
  const int tid = threadIdx.x, wid = tid >> 6, lane = tid & 63;

  __shared__ float red[4];
  __shared__ float bc[2];

  float v0 = xr[tid], v1 = xr[tid + 256];
  float s = v0 + v1;
#pragma unroll
  for (int off = 32; off; off >>= 1) s += __shfl_xor(s, off);
  if (lane == 0) red[wid] = s;
  __syncthreads();
  if (tid == 0) bc[0] = (red[0] + red[1] + red[2] + red[3]) * (1.0f / Dn);
  __syncthreads();
  const float m = bc[0];
  const float d0 = v0 - m, d1 = v1 - m;
  float s2 = d0 * d0 + d1 * d1;
#pragma unroll
  for (int off = 32; off; off >>= 1) s2 += __shfl_xor(s2, off);
  if (lane == 0) red[wid] = s2;
  __syncthreads();
  if (tid == 0)
    bc[1] = rsqrtf((red[0] + red[1] + red[2] + red[3]) * (1.0f / Dn) + 1e-5f);
  __syncthreads();
  const float r = bc[1];

  float o0 = d0 * r * g[tid] + b[tid];
  float o1 = d1 * r * g[tid + 256] + b[tid + 256];
  if (GLU) {
    const float w0 = pw1w[0], w1 = pw1w[1], c0 = pw1b[0], c1 = pw1b[1];
    o0 = (w0 * o0 + c0) * (1.0f / (1.0f + expf(-(w1 * o0 + c1))));
    o1 = (w0 * o1 + c0) * (1.0f / (1.0f + expf(-(w1 * o1 + c1))));
  }
  if (BF) {
    yb[(size_t)row * Dn + tid] = f2b(o0);
    yb[(size_t)row * Dn + tid + 256] = f2b(o1);
  } else {
    yf[(size_t)row * Dn + tid] = o0;
    yf[(size_t)row * Dn + tid + 256] = o1;
  }
}

// ---------------------------------------------------------------------------
// wcvt8: all 8 weight transposes/converts in one launch.
// Segment table (32x32 tiles): fi1 1024 | fi2 1024 | q/k/v/o 256 each | fo1
// 1024 | fo2 1024 = 5120 blocks. W (K x N fp32) -> Wt (N x K bf16).
// ---------------------------------------------------------------------------
__global__ __launch_bounds__(256) void wcvt8_kernel(
    const float* s0, const float* s1, const float* s2, const float* s3,
    const float* s4, const float* s5, const float* s6, const float* s7,
    ushort* d0, ushort* d1, ushort* d2, ushort* d3, ushort* d4, ushort* d5,
    ushort* d6, ushort* d7) {
  int bid = blockIdx.x;
  const float* W;
  ushort* Wt;
  int K, N, tile;
  if (bid < 1024)      { W = s0; Wt = d0; K = Dn; N = Fn; tile = bid; }
  else if (bid < 2048) { W = s1; Wt = d1; K = Fn; N = Dn; tile = bid - 1024; }
  else if (bid < 2304) { W = s2; Wt = d2; K = Dn; N = Dn; tile = bid - 2048; }
  else if (bid < 2560) { W = s3; Wt = d3; K = Dn; N = Dn; tile = bid - 2304; }
  else if (bid < 2816) { W = s4; Wt = d4; K = Dn; N = Dn; tile = bid - 2560; }
  else if (bid < 3072) { W = s5; Wt = d5; K = Dn; N = Dn; tile = bid - 2816; }
  else if (bid < 4096) { W = s6; Wt = d6; K = Dn; N = Fn; tile = bid - 3072; }
  else                 { W = s7; Wt = d7; K = Fn; N = Dn; tile = bid - 4096; }
  const int nt = N / 32;
  const int n0 = (tile % nt) * 32, k0 = (tile / nt) * 32;

  __shared__ float tilebuf[32][33];
  const int tx = threadIdx.x & 31, ty = threadIdx.x >> 5;
#pragma unroll
  for (int i = 0; i < 4; ++i) {
    int k = ty + i * 8;
    tilebuf[k][tx] = W[(size_t)(k0 + k) * N + n0 + tx];
  }
  __syncthreads();
#pragma unroll
  for (int i = 0; i < 4; ++i) {
    int r = ty + i * 8;
    Wt[(size_t)(n0 + r) * K + k0 + tx] = f2b(tilebuf[tx][r]);
  }
}

// ---------------------------------------------------------------------------
// bf16 MFMA GEMM (NT), tile BM x BN, 4 waves (2x2), wave tile BM/2 x BN/2.
// MODE 0: relu -> bf16 Cb     MODE 1: C = res + 0.5*v (fp32)
// MODE 3: C = res + v (fp32)  MODE 4: Cb = bf16(v), 3-segment bias (QKV)
// ---------------------------------------------------------------------------
template <int MODE, int BM, int BN>
__global__ __launch_bounds__(256) void mgemm_kernel(
    const ushort* __restrict__ A, const ushort* __restrict__ Bt,
    const float* __restrict__ bias, const float* __restrict__ bias2,
    const float* __restrict__ bias3, const float* __restrict__ res,
    float* __restrict__ C, ushort* __restrict__ Cb, int M, int N, int K) {
  constexpr int NFM = BM / 32;
  constexpr int NFN = BN / 32;
  __shared__ ushort As[BM * 64];
  __shared__ ushort Bs[BN * 64];
  const int bm = blockIdx.y * BM, bn = blockIdx.x * BN;
  const int tid = threadIdx.x;
  const int wid = tid >> 6, l = tid & 63;
  const int wm = wid >> 1, wn = wid & 1;
  const int l16 = l & 15, lhi = l >> 4;

  f4 acc[NFM][NFN] = {};

  for (int k0 = 0; k0 < K; k0 += 64) {
#pragma unroll
    for (int i = 0; i < BM * 8 / 256; ++i) {
      int slot = tid + i * 256;
      int row = slot >> 3, c8 = slot & 7;
      gload16(A + (size_t)(bm + row) * K + k0 + c8 * 8, &As[slot * 8]);
    }
#pragma unroll
    for (int i = 0; i < BN * 8 / 256; ++i) {
      int slot = tid + i * 256;
      int row = slot >> 3, c8 = slot & 7;
      gload16(Bt + (size_t)(bn + row) * K + k0 + c8 * 8, &Bs[slot * 8]);
    }
    __syncthreads();
#pragma unroll
    for (int ks = 0; ks < 2; ++ks) {
      bhalf8 a[NFM], b[NFN];
#pragma unroll
      for (int mi = 0; mi < NFM; ++mi)
        a[mi] = *(const bhalf8*)&As[(wm * (BM / 2) + mi * 16 + l16) * 64 +
                                    ks * 32 + lhi * 8];
#pragma unroll
      for (int ni = 0; ni < NFN; ++ni)
        b[ni] = *(const bhalf8*)&Bs[(wn * (BN / 2) + ni * 16 + l16) * 64 +
                                    ks * 32 + lhi * 8];
#pragma unroll
      for (int mi = 0; mi < NFM; ++mi)
#pragma unroll
        for (int ni = 0; ni < NFN; ++ni)
          acc[mi][ni] = __builtin_amdgcn_mfma_f32_16x16x32_bf16(
              a[mi], b[ni], acc[mi][ni], 0, 0, 0);
    }
    __syncthreads();
  }

#pragma unroll
  for (int mi = 0; mi < NFM; ++mi) {
#pragma unroll
    for (int ni = 0; ni < NFN; ++ni) {
      const int col = bn + wn * (BN / 2) + ni * 16 + l16;
      float bv;
      if (MODE == 4)
        bv = col < 512 ? bias[col]
                       : (col < 1024 ? bias2[col - 512] : bias3[col - 1024]);
      else
        bv = bias[col];
#pragma unroll
      for (int r = 0; r < 4; ++r) {
        const int row = bm + wm * (BM / 2) + mi * 16 + lhi * 4 + r;
        float v = acc[mi][ni][r] + bv;
        const size_t off = (size_t)row * N + col;
        if (MODE == 0) {
          Cb[off] = f2b(fmaxf(v, 0.0f));
        } else if (MODE == 4) {
          Cb[off] = f2b(v);
        } else {
          if (MODE == 1) v = res[off] + 0.5f * v;
          if (MODE == 3) v = res[off] + v;
          C[off] = v;
        }
      }
    }
  }
}

// ---------------------------------------------------------------------------
// bmm: Sc16[bh][t][s] = bf16( q . pos_k[t,s,:] ); PASS=1 also writes the
// pos_k passthrough copy. q from qkv buffer (row stride QS=1536).
// ---------------------------------------------------------------------------
template <int PASS>
__global__ __launch_bounds__(256) void bmm_kernel(const ushort* __restrict__ qkv,
                                                  const float* __restrict__ pk,
                                                  ushort* __restrict__ Sc16,
                                                  float* __restrict__ pkout) {
  const int s0 = blockIdx.x * 256;
  const int t = blockIdx.y;
  const int tid = threadIdx.x, wid = tid >> 6, l = tid & 63;
  const int l16 = l & 15, lhi = l >> 4;

  __shared__ ushort Qs[32 * 64];
  __shared__ ushort Ps[256 * 64];  // pos_k staging; reused for output transpose

  {
    int row = tid >> 3, c8 = tid & 7;
    int bq = row >> 3, hq = row & 7;
    *(uint4*)&Qs[row * 64 + c8 * 8] = *(const uint4*)(
        qkv + ((size_t)(bq * Tn + t)) * QS + hq * 64 + c8 * 8);
  }
#pragma unroll
  for (int i = 0; i < 16; ++i) {
    int slot = tid + i * 256;
    int sr = slot >> 4, c4 = slot & 15;
    const size_t goff = ((size_t)t * Tn + s0 + sr) * Dk + c4 * 4;
    const float4 p = *(const float4*)(pk + goff);
    if (PASS) *(float4*)(pkout + goff) = p;
    ushort4 u;
    u.x = f2b(p.x);
    u.y = f2b(p.y);
    u.z = f2b(p.z);
    u.w = f2b(p.w);
    *(ushort4*)&Ps[sr * 64 + c4 * 4] = u;
  }
  __syncthreads();

  f4 acc[2][4] = {};
#pragma unroll
  for (int ks = 0; ks < 2; ++ks) {
    bhalf8 a[2], b[4];
#pragma unroll
    for (int mi = 0; mi < 2; ++mi)
      a[mi] = *(const bhalf8*)&Qs[(mi * 16 + l16) * 64 + ks * 32 + lhi * 8];
#pragma unroll
    for (int ni = 0; ni < 4; ++ni)
      b[ni] = *(const bhalf8*)&Ps[(wid * 64 + ni * 16 + l16) * 64 + ks * 32 +
                                  lhi * 8];
#pragma unroll
    for (int mi = 0; mi < 2; ++mi)
#pragma unroll
      for (int ni = 0; ni < 4; ++ni)
        acc[mi][ni] = __builtin_amdgcn_mfma_f32_16x16x32_bf16(
            a[mi], b[ni], acc[mi][ni], 0, 0, 0);
  }

  __syncthreads();  // all waves done reading Ps (pos_k staging)
#pragma unroll
  for (int mi = 0; mi < 2; ++mi)
#pragma unroll
    for (int ni = 0; ni < 4; ++ni)
#pragma unroll
      for (int r = 0; r < 4; ++r) {
        const int bh = mi * 16 + lhi * 4 + r;
        const int sl = wid * 64 + ni * 16 + l16;
        Ps[bh * 256 + sl] = f2b(acc[mi][ni][r]);
      }
  __syncthreads();
#pragma unroll
  for (int i = 0; i < 4; ++i) {
    int idx = tid + i * 256;
    int bh = idx >> 5, sc = (idx & 31) * 8;
    *(uint4*)&Sc16[((size_t)bh * Tn + t) * Tn + s0 + sc] =
        *(const uint4*)&Ps[bh * 256 + sc];
  }
}

// ---------------------------------------------------------------------------
// fattn: flash attention. q/k/v from qkv buffer (stride QS; k at +512, v at
// +1024). Bm tile staged into Ps via gload16 with both-sides XOR swizzle.
// ---------------------------------------------------------------------------
__global__ __launch_bounds__(256) void fattn_kernel(
    const ushort* __restrict__ qkv, const ushort* __restrict__ Sc16,
    const uint* __restrict__ mbits, ushort* __restrict__ ctxb) {
  const int bh = blockIdx.y;
  const int b = bh >> 3, h = bh & 7;
  const int t0 = blockIdx.x * 128;
  const int tid = threadIdx.x;
  const int wid = tid >> 6, l = tid & 63;
  const int l16 = l & 15, lhi = l >> 4;

  __shared__ ushort KV[8448];       // K [128][64] (8192) / V^T [64][132] (8448)
  __shared__ ushort Ps[128 * 128];  // Bm stage -> P (swizzled); also Q staging

  // Q fragments -> registers (staged via Ps)
  bhalf8 qa[2][2];
  {
#pragma unroll
    for (int i = 0; i < 4; ++i) {
      int slot = tid + i * 256;
      int row = slot >> 3, c8 = slot & 7;
      gload16(qkv + ((size_t)(b * Tn + t0 + row)) * QS + h * 64 + c8 * 8,
              &Ps[slot * 8]);
    }
    __syncthreads();
#pragma unroll
    for (int mi = 0; mi < 2; ++mi)
#pragma unroll
      for (int ks = 0; ks < 2; ++ks)
        qa[mi][ks] = *(const bhalf8*)&Ps[(wid * 32 + mi * 16 + l16) * 64 +
                                         ks * 32 + lhi * 8];
    __syncthreads();
  }

  f4 oacc[2][4] = {};
  float mrow[2][4], lrow[2][4];
#pragma unroll
  for (int mi = 0; mi < 2; ++mi)
#pragma unroll
    for (int r = 0; r < 4; ++r) {
      mrow[mi][r] = -3.0e38f;
      lrow[mi][r] = 0.0f;
    }

  const float scale = 0.125f;
  for (int s0 = 0; s0 < Tn; s0 += 128) {
    // stage K [128 s][64 dk]
#pragma unroll
    for (int i = 0; i < 4; ++i) {
      int slot = tid + i * 256;
      int row = slot >> 3, c8 = slot & 7;
      gload16(qkv + ((size_t)(b * Tn + s0 + row)) * QS + 512 + h * 64 + c8 * 8,
              &KV[slot * 8]);
    }
    // stage Bm tile [128 t][128 s] u16 into Ps, source pre-swizzled (rule #21)
#pragma unroll
    for (int i = 0; i < 8; ++i) {
      int slot = tid + i * 256;            // 2048 slots x 16 B
      int row = slot >> 4, c16 = slot & 15;
      int cb = (c16 * 16) ^ ((row & 7) << 4);
      gload16(
          (const char*)(Sc16 + ((size_t)bh * Tn + t0 + row) * Tn + s0) + cb,
          (char*)Ps + slot * 16);
    }
    __syncthreads();  // K + Bm visible

    // acc init = Bm from LDS (swizzled read)
    f4 accs[2][8];
#pragma unroll
    for (int mi = 0; mi < 2; ++mi)
#pragma unroll
      for (int r = 0; r < 4; ++r) {
        const int lr = wid * 32 + mi * 16 + lhi * 4 + r;
#pragma unroll
        for (int ni = 0; ni < 8; ++ni) {
          const int cb = ((ni * 16 + l16) * 2) ^ ((lr & 7) << 4);
          accs[mi][ni][r] = b2f(*(const ushort*)((const char*)Ps + lr * 256 + cb));
        }
      }

    // QK^T
#pragma unroll
    for (int ks = 0; ks < 2; ++ks) {
      bhalf8 bb[8];
#pragma unroll
      for (int ni = 0; ni < 8; ++ni)
        bb[ni] = *(const bhalf8*)&KV[(ni * 16 + l16) * 64 + ks * 32 + lhi * 8];
#pragma unroll
      for (int mi = 0; mi < 2; ++mi)
#pragma unroll
        for (int ni = 0; ni < 8; ++ni)
          accs[mi][ni] = __builtin_amdgcn_mfma_f32_16x16x32_bf16(
              qa[mi][ks], bb[ni], accs[mi][ni], 0, 0, 0);
    }

    // online softmax (in regs) + P write into Ps (same swizzle; own rows only)
#pragma unroll
    for (int mi = 0; mi < 2; ++mi)
#pragma unroll
      for (int r = 0; r < 4; ++r) {
        const int trow = t0 + wid * 32 + mi * 16 + lhi * 4 + r;
        const uint* mw = mbits + ((size_t)b * Tn + trow) * 32 + (s0 >> 5);
        const uint w[4] = {mw[0], mw[1], mw[2], mw[3]};
        float p[8];
        float rm = -3.0e38f;
#pragma unroll
        for (int ni = 0; ni < 8; ++ni) {
          float v = accs[mi][ni][r] * scale;
          const uint bit = (w[ni >> 1] >> ((ni & 1) * 16 + l16)) & 1u;
          v = bit ? v : -3.0e38f;
          p[ni] = v;
          rm = fmaxf(rm, v);
        }
#pragma unroll
        for (int off = 8; off; off >>= 1) rm = fmaxf(rm, __shfl_xor(rm, off));
        const float mnew = fmaxf(mrow[mi][r], rm);
        const float sold = __expf(mrow[mi][r] - mnew);
        mrow[mi][r] = mnew;
        float rs = 0.0f;
#pragma unroll
        for (int ni = 0; ni < 8; ++ni) {
          const float e = __expf(p[ni] - mnew);
          rs += e;
          p[ni] = e;
        }
#pragma unroll
        for (int off = 8; off; off >>= 1) rs += __shfl_xor(rs, off);
        lrow[mi][r] = lrow[mi][r] * sold + rs;
#pragma unroll
        for (int ni = 0; ni < 4; ++ni) oacc[mi][ni][r] *= sold;
        const int lr = wid * 32 + mi * 16 + lhi * 4 + r;
#pragma unroll
        for (int ni = 0; ni < 8; ++ni) {
          const int byte =
              (lr * 256 + (((ni * 16 + l16) * 2) ^ ((lr & 7) << 4)));
          *(ushort*)((char*)Ps + byte) = f2b(p[ni]);
        }
      }
    __syncthreads();  // QK done reading KV; P written

    // stage V^T [64 d][132 stride], all 128 s rows
#pragma unroll
    for (int i = 0; i < 4; ++i) {
      int slot = tid + i * 256;
      int sr = slot >> 3, c8 = slot & 7;
      const uint4 raw = *(const uint4*)(
          qkv + ((size_t)(b * Tn + s0 + sr)) * QS + 1024 + h * 64 + c8 * 8);
      const ushort* e = (const ushort*)&raw;
#pragma unroll
      for (int j = 0; j < 8; ++j) KV[(c8 * 8 + j) * 132 + sr] = e[j];
    }
    __syncthreads();  // V^T + P visible

    // PV (P read with matching swizzle: row lr, col ks*32+lhi*8 .. +8)
#pragma unroll
    for (int ks = 0; ks < 4; ++ks) {
      bhalf8 a[2], bb[4];
#pragma unroll
      for (int mi = 0; mi < 2; ++mi) {
        const int lr = wid * 32 + mi * 16 + l16;
        const int byte = (lr * 256 + ((ks * 64 + lhi * 16) ^ ((lr & 7) << 4)));
        a[mi] = *(const bhalf8*)((char*)Ps + byte);
      }
#pragma unroll
      for (int ni = 0; ni < 4; ++ni)
        bb[ni] = *(const bhalf8*)&KV[(ni * 16 + l16) * 132 + ks * 32 + lhi * 8];
#pragma unroll
      for (int mi = 0; mi < 2; ++mi)
#pragma unroll
        for (int ni = 0; ni < 4; ++ni)
          oacc[mi][ni] = __builtin_amdgcn_mfma_f32_16x16x32_bf16(
              a[mi], bb[ni], oacc[mi][ni], 0, 0, 0);
    }
    __syncthreads();  // protect KV/Ps for next iter
  }

#pragma unroll
  for (int mi = 0; mi < 2; ++mi)
#pragma unroll
    for (int r = 0; r < 4; ++r) {
      const float inv = (mrow[mi][r] <= -1.0e37f)
                            ? 0.0f
                            : 1.0f / fmaxf(lrow[mi][r], 1e-30f);
      const int t = t0 + wid * 32 + mi * 16 + lhi * 4 + r;
#pragma unroll
      for (int ni = 0; ni < 4; ++ni) {
        const int d = ni * 16 + l16;
        ctxb[((size_t)(b * Tn + t)) * Dn + h * 64 + d] =
            f2b(oacc[mi][ni][r] * inv);
      }
    }
}

// ---------------------------------------------------------------------------
// conv2: depthwise conv1d (K=31) + ReLU + pw2 + residual; register window.
// ---------------------------------------------------------------------------
__global__ __launch_bounds__(256) void conv2_kernel(
    const float* __restrict__ y, const float* __restrict__ dww,
    const float* __restrict__ dwb, const float* __restrict__ pw2w,
    const float* __restrict__ pw2b, float* __restrict__ x) {
  const int b = blockIdx.z;
  const int d0 = blockIdx.y * 256;
  const int t0 = blockIdx.x * 16;
  const int tid = threadIdx.x;
  const int d = d0 + tid;

  __shared__ float wlds[256 * Kw];
#pragma unroll
  for (int i = 0; i < Kw; ++i)
    wlds[i * 256 + tid] = dww[(size_t)d0 * Kw + i * 256 + tid];
  __syncthreads();

  float w[Kw];
#pragma unroll
  for (int k = 0; k < Kw; ++k) w[k] = wlds[tid * Kw + k];

  float v[46];
#pragma unroll
  for (int i = 0; i < 46; ++i) {
    int t = t0 - 15 + i;
    v[i] = (t >= 0 && t < Tn) ? y[((size_t)b * Tn + t) * Dn + d] : 0.0f;
  }

  const float bias = dwb[d], w2 = pw2w[0], c2 = pw2b[0];
#pragma unroll
  for (int j = 0; j < 16; ++j) {
    float acc = bias;
#pragma unroll
    for (int k = 0; k < Kw; ++k) acc += w[k] * v[j + k];
    acc = fmaxf(acc, 0.0f);
    const size_t idx = ((size_t)b * Tn + t0 + j) * Dn + d;
    x[idx] = x[idx] + w2 * acc + c2;
  }
}

// ---------------------------------------------------------------------------
// maskcvt: int32 mask -> fp32 passthrough output AND packed bits (1 bit/s).
// ---------------------------------------------------------------------------
__global__ __launch_bounds__(256) void maskcvt_kernel(
    const int* __restrict__ in, float* __restrict__ outf,
    uint* __restrict__ mbits) {
  const size_t idx = (size_t)blockIdx.x * 256 + threadIdx.x;
  const size_t base = idx * 32;
  uint bits = 0;
#pragma unroll
  for (int j = 0; j < 8; ++j) {
    const int4 v = *(const int4*)(in + base + j * 4);
    float4 f;
    f.x = (float)v.x;
    f.y = (float)v.y;
    f.z = (float)v.z;
    f.w = (float)v.w;
    *(float4*)(outf + base + j * 4) = f;
    bits |= (v.x != 0 ? 1u : 0u) << (j * 4 + 0);
    bits |= (v.y != 0 ? 1u : 0u) << (j * 4 + 1);
    bits |= (v.z != 0 ? 1u : 0u) << (j * 4 + 2);
    bits |= (v.w != 0 ? 1u : 0u) << (j * 4 + 3);
  }
  mbits[idx] = bits;
}

// ---------------------------------------------------------------------------
extern "C" void kernel_launch(void* const* d_in, const int* in_sizes, int n_in,
                              void* d_out, int out_size, void* d_ws,
                              size_t ws_size, hipStream_t stream) {
  const float* x = (const float*)d_in[0];
  const float* pos_k = (const float*)d_in[1];
  const int* mask = (const int*)d_in[2];
  const float* fi_g = (const float*)d_in[3];
  const float* fi_b = (const float*)d_in[4];
  const float* fi_w1 = (const float*)d_in[5];
  const float* fi_b1 = (const float*)d_in[6];
  const float* fi_w2 = (const float*)d_in[7];
  const float* fi_b2 = (const float*)d_in[8];
  const float* at_g = (const float*)d_in[9];
  const float* at_b = (const float*)d_in[10];
  const float* wq = (const float*)d_in[11];
  const float* bq = (const float*)d_in[12];
  const float* wk = (const float*)d_in[13];
  const float* bk = (const float*)d_in[14];
  const float* wv = (const float*)d_in[15];
  const float* bv = (const float*)d_in[16];
  const float* wo = (const float*)d_in[17];
  const float* bo = (const float*)d_in[18];
  const float* cv_g = (const float*)d_in[19];
  const float* cv_b = (const float*)d_in[20];
  const float* pw1w = (const float*)d_in[21];
  const float* pw1b = (const float*)d_in[22];
  const float* dww = (const float*)d_in[23];
  const float* dwb = (const float*)d_in[24];
  const float* pw2w = (const float*)d_in[25];
  const float* pw2b = (const float*)d_in[26];
  const float* fo_g = (const float*)d_in[27];
  const float* fo_b = (const float*)d_in[28];
  const float* fo_w1 = (const float*)d_in[29];
  const float* fo_b1 = (const float*)d_in[30];
  const float* fo_w2 = (const float*)d_in[31];
  const float* fo_b2 = (const float*)d_in[32];
  const float* fl_g = (const float*)d_in[33];
  const float* fl_b = (const float*)d_in[34];

  float* out = (float*)d_out;

  // ws front: xcur | y | mbits (always)
  float* xcur = (float*)d_ws;
  float* y = xcur + N_OUT;
  uint* mbits = (uint*)(y + N_OUT);  // 512 KB

  // big scratch: prefer ws (enables fused pos_k passthrough); else out region
  const size_t NEED = (size_t)206 << 20;
  const bool fused = ws_size >= NEED;
  char* sp = fused ? (char*)(mbits + N_MASK / 32) : (char*)(out + N_OUT);
  auto alloc16 = [&](size_t elems) {
    ushort* p = (ushort*)sp;
    sp += ((elems * 2 + 255) & ~(size_t)255);
    return p;
  };
  ushort* Sc16 = alloc16((size_t)32 * Tn * Tn);  // 67 MB
  ushort* wt_fi1 = alloc16((size_t)Fn * Dn);
  ushort* wt_fi2 = alloc16((size_t)Dn * Fn);
  ushort* wt_qkv = alloc16((size_t)QS * Dn);  // [1536][512]
  ushort* wt_o = alloc16((size_t)Dn * Dn);
  ushort* wt_fo1 = alloc16((size_t)Fn * Dn);
  ushort* wt_fo2 = alloc16((size_t)Dn * Fn);
  ushort* ybf = alloc16(N_OUT);
  ushort* hbf = alloc16((size_t)Bsz * Tn * Fn);
  ushort* ctxbf = alloc16(N_OUT);
  ushort* qkvbf = alloc16((size_t)Bsz * Tn * QS);  // 25 MB

  const int M = Bsz * Tn;  // 4096
  const dim3 blk256(256);
  const dim3 grid_rows(M);
  const dim3 gF(Fn / 128, M / 128);    // 128x128, N=2048
  const dim3 gD64(Dn / 64, M / 64);    // 64x64,  N=512
  const dim3 gRect(Dn / 64, M / 128);  // 128x64, N=512
  const dim3 gQKV(QS / 64, M / 128);   // 128x64, N=1536: 24x32

  // mask passthrough + bit-pack (early; flash needs mbits)
  maskcvt_kernel<<<dim3(N_MASK / 32 / 256), blk256, 0, stream>>>(
      mask, out + N_OUT + N_POSK, mbits);

  // all weight conversions in one launch
  wcvt8_kernel<<<dim3(5120), blk256, 0, stream>>>(
      fi_w1, fi_w2, wq, wk, wv, wo, fo_w1, fo_w2, wt_fi1, wt_fi2, wt_qkv,
      wt_qkv + (size_t)Dn * Dn, wt_qkv + (size_t)2 * Dn * Dn, wt_o, wt_fo1,
      wt_fo2);

  // macaron FFN-in (first LN reads x directly; MODE 1 res=x writes xcur)
  ln_kernel<0, 1><<<grid_rows, blk256, 0, stream>>>(x, fi_g, fi_b, nullptr,
                                                    ybf, nullptr, nullptr);
  mgemm_kernel<0, 128, 128><<<gF, blk256, 0, stream>>>(
      ybf, wt_fi1, fi_b1, nullptr, nullptr, nullptr, nullptr, hbf, M, Fn, Dn);
  mgemm_kernel<1, 128, 64><<<gRect, blk256, 0, stream>>>(
      hbf, wt_fi2, fi_b2, nullptr, nullptr, x, xcur, nullptr, M, Dn, Fn);

  // attention: fused QKV projection (N=1536)
  ln_kernel<0, 1><<<grid_rows, blk256, 0, stream>>>(xcur, at_g, at_b, nullptr,
                                                    ybf, nullptr, nullptr);
  mgemm_kernel<4, 128, 64><<<gQKV, blk256, 0, stream>>>(
      ybf, wt_qkv, bq, bk, bv, nullptr, nullptr, qkvbf, M, QS, Dn);

  if (fused)
    bmm_kernel<1><<<dim3(4, Tn), blk256, 0, stream>>>(qkvbf, pos_k, Sc16,
                                                      out + N_OUT);
  else
    bmm_kernel<0><<<dim3(4, Tn), blk256, 0, stream>>>(qkvbf, pos_k, Sc16,
                                                      nullptr);

  fattn_kernel<<<dim3(Tn / 128, 32), blk256, 0, stream>>>(qkvbf, Sc16, mbits,
                                                          ctxbf);

  mgemm_kernel<3, 64, 64><<<gD64, blk256, 0, stream>>>(
      ctxbf, wt_o, bo, nullptr, nullptr, xcur, xcur, nullptr, M, Dn, Dn);

  // conv module
  ln_kernel<1, 0><<<grid_rows, blk256, 0, stream>>>(xcur, cv_g, cv_b, y,
                                                    nullptr, pw1w, pw1b);
  conv2_kernel<<<dim3(Tn / 16, 2, Bsz), blk256, 0, stream>>>(y, dww, dwb, pw2w,
                                                             pw2b, xcur);

  // macaron FFN-out
  ln_kernel<0, 1><<<grid_rows, blk256, 0, stream>>>(xcur, fo_g, fo_b, nullptr,
                                                    ybf, nullptr, nullptr);
  mgemm_kernel<0, 128, 128><<<gF, blk256, 0, stream>>>(
      ybf, wt_fo1, fo_b1, nullptr, nullptr, nullptr, nullptr, hbf, M, Fn, Dn);
  mgemm_kernel<1, 128, 64><<<gRect, blk256, 0, stream>>>(
      hbf, wt_fo2, fo_b2, nullptr, nullptr, xcur, xcur, nullptr, M, Dn, Fn);

  // final LN -> d_out[0]
  ln_kernel<0, 0><<<grid_rows, blk256, 0, stream>>>(xcur, fl_g, fl_b, out,
                                                    nullptr, nullptr, nullptr);

  // pos_k passthrough (only if not fused into bmm)
  if (!fused)
    hipMemcpyAsync(out + N_OUT, pos_k, N_POSK * sizeof(float),
                   hipMemcpyDeviceToDevice, stream);
}

// Round 10
// 363.785 us; speedup vs baseline: 1.1509x; 1.0704x over previous
//
#include <hip/hip_runtime.h>
#include <math.h>

static constexpr int Bsz = 4, Tn = 1024, Dn = 512, Hn = 8, Fn = 2048, Kw = 31, Dk = 64;
static constexpr int QS = 3 * Dn;  // 1536, qkv row stride
static constexpr size_t N_OUT  = (size_t)Bsz * Tn * Dn;   // 2,097,152
static constexpr size_t N_POSK = (size_t)Tn * Tn * Dk;    // 67,108,864
static constexpr size_t N_MASK = (size_t)Bsz * Tn * Tn;   // 4,194,304

typedef __attribute__((ext_vector_type(8))) short bhalf8;  // 8 bf16 (4 VGPR)
typedef __attribute__((ext_vector_type(4))) float f4;      // MFMA C/D

__device__ __forceinline__ ushort f2b(float f) {
  uint b = __float_as_uint(f);
  uint r = (b + 0x7FFFu + ((b >> 16) & 1u)) >> 16;
  return (ushort)r;
}
__device__ __forceinline__ float b2f(ushort u) {
  return __uint_as_float((uint)u << 16);
}

// async global->LDS, 16 B per lane
typedef const __attribute__((address_space(1))) unsigned int* gp1_t;
typedef __attribute__((address_space(3))) unsigned int* lp3_t;
__device__ __forceinline__ void gload16(const void* g, void* l) {
  __builtin_amdgcn_global_load_lds((gp1_t)g, (lp3_t)l, 16, 0, 0);
}

// ---------------------------------------------------------------------------
// LayerNorm; BF=1 -> bf16 output, BF=0 -> fp32 output. GLU on fp32 path.
// ---------------------------------------------------------------------------
template <int GLU, int BF>
__global__ __launch_bounds__(256) void ln_kernel(
    const float* __restrict__ x, const float* __restrict__ g,
    const float* __restrict__ b, float* __restrict__ yf,
    ushort* __restrict__ yb, const float* __restrict__ pw1w,
    const float* __restrict__ pw1b) {
  const int row = blockIdx.x;
  const float* xr = x + (size_t)row * Dn;
  const int tid = threadIdx.x, wid = tid >> 6, lane = tid & 63;

  __shared__ float red[4];
  __shared__ float bc[2];

  float v0 = xr[tid], v1 = xr[tid + 256];
  float s = v0 + v1;
#pragma unroll
  for (int off = 32; off; off >>= 1) s += __shfl_xor(s, off);
  if (lane == 0) red[wid] = s;
  __syncthreads();
  if (tid == 0) bc[0] = (red[0] + red[1] + red[2] + red[3]) * (1.0f / Dn);
  __syncthreads();
  const float m = bc[0];
  const float d0 = v0 - m, d1 = v1 - m;
  float s2 = d0 * d0 + d1 * d1;
#pragma unroll
  for (int off = 32; off; off >>= 1) s2 += __shfl_xor(s2, off);
  if (lane == 0) red[wid] = s2;
  __syncthreads();
  if (tid == 0)
    bc[1] = rsqrtf((red[0] + red[1] + red[2] + red[3]) * (1.0f / Dn) + 1e-5f);
  __syncthreads();
  const float r = bc[1];

  float o0 = d0 * r * g[tid] + b[tid];
  float o1 = d1 * r * g[tid + 256] + b[tid + 256];
  if (GLU) {
    const float w0 = pw1w[0], w1 = pw1w[1], c0 = pw1b[0], c1 = pw1b[1];
    o0 = (w0 * o0 + c0) * (1.0f / (1.0f + expf(-(w1 * o0 + c1))));
    o1 = (w0 * o1 + c0) * (1.0f / (1.0f + expf(-(w1 * o1 + c1))));
  }
  if (BF) {
    yb[(size_t)row * Dn + tid] = f2b(o0);
    yb[(size_t)row * Dn + tid + 256] = f2b(o1);
  } else {
    yf[(size_t)row * Dn + tid] = o0;
    yf[(size_t)row * Dn + tid + 256] = o1;
  }
}

// ---------------------------------------------------------------------------
// wcvt8: all 8 weight transposes/converts in one launch.
// ---------------------------------------------------------------------------
__global__ __launch_bounds__(256) void wcvt8_kernel(
    const float* s0, const float* s1, const float* s2, const float* s3,
    const float* s4, const float* s5, const float* s6, const float* s7,
    ushort* d0, ushort* d1, ushort* d2, ushort* d3, ushort* d4, ushort* d5,
    ushort* d6, ushort* d7) {
  int bid = blockIdx.x;
  const float* W;
  ushort* Wt;
  int K, N, tile;
  if (bid < 1024)      { W = s0; Wt = d0; K = Dn; N = Fn; tile = bid; }
  else if (bid < 2048) { W = s1; Wt = d1; K = Fn; N = Dn; tile = bid - 1024; }
  else if (bid < 2304) { W = s2; Wt = d2; K = Dn; N = Dn; tile = bid - 2048; }
  else if (bid < 2560) { W = s3; Wt = d3; K = Dn; N = Dn; tile = bid - 2304; }
  else if (bid < 2816) { W = s4; Wt = d4; K = Dn; N = Dn; tile = bid - 2560; }
  else if (bid < 3072) { W = s5; Wt = d5; K = Dn; N = Dn; tile = bid - 2816; }
  else if (bid < 4096) { W = s6; Wt = d6; K = Dn; N = Fn; tile = bid - 3072; }
  else                 { W = s7; Wt = d7; K = Fn; N = Dn; tile = bid - 4096; }
  const int nt = N / 32;
  const int n0 = (tile % nt) * 32, k0 = (tile / nt) * 32;

  __shared__ float tilebuf[32][33];
  const int tx = threadIdx.x & 31, ty = threadIdx.x >> 5;
#pragma unroll
  for (int i = 0; i < 4; ++i) {
    int k = ty + i * 8;
    tilebuf[k][tx] = W[(size_t)(k0 + k) * N + n0 + tx];
  }
  __syncthreads();
#pragma unroll
  for (int i = 0; i < 4; ++i) {
    int r = ty + i * 8;
    Wt[(size_t)(n0 + r) * K + k0 + tx] = f2b(tilebuf[tx][r]);
  }
}

// ---------------------------------------------------------------------------
// bf16 MFMA GEMM (NT), tile BM x BN, 4 waves (2x2), wave tile BM/2 x BN/2.
// MODE 0: relu -> bf16 Cb     MODE 1: C = res + 0.5*v (fp32)
// MODE 3: C = res + v (fp32)  MODE 4: Cb = bf16(v), 3-segment bias (QKV)
// ---------------------------------------------------------------------------
template <int MODE, int BM, int BN>
__global__ __launch_bounds__(256) void mgemm_kernel(
    const ushort* __restrict__ A, const ushort* __restrict__ Bt,
    const float* __restrict__ bias, const float* __restrict__ bias2,
    const float* __restrict__ bias3, const float* __restrict__ res,
    float* __restrict__ C, ushort* __restrict__ Cb, int M, int N, int K) {
  constexpr int NFM = BM / 32;
  constexpr int NFN = BN / 32;
  __shared__ ushort As[BM * 64];
  __shared__ ushort Bs[BN * 64];
  const int bm = blockIdx.y * BM, bn = blockIdx.x * BN;
  const int tid = threadIdx.x;
  const int wid = tid >> 6, l = tid & 63;
  const int wm = wid >> 1, wn = wid & 1;
  const int l16 = l & 15, lhi = l >> 4;

  f4 acc[NFM][NFN] = {};

  for (int k0 = 0; k0 < K; k0 += 64) {
#pragma unroll
    for (int i = 0; i < BM * 8 / 256; ++i) {
      int slot = tid + i * 256;
      int row = slot >> 3, c8 = slot & 7;
      gload16(A + (size_t)(bm + row) * K + k0 + c8 * 8, &As[slot * 8]);
    }
#pragma unroll
    for (int i = 0; i < BN * 8 / 256; ++i) {
      int slot = tid + i * 256;
      int row = slot >> 3, c8 = slot & 7;
      gload16(Bt + (size_t)(bn + row) * K + k0 + c8 * 8, &Bs[slot * 8]);
    }
    __syncthreads();
#pragma unroll
    for (int ks = 0; ks < 2; ++ks) {
      bhalf8 a[NFM], b[NFN];
#pragma unroll
      for (int mi = 0; mi < NFM; ++mi)
        a[mi] = *(const bhalf8*)&As[(wm * (BM / 2) + mi * 16 + l16) * 64 +
                                    ks * 32 + lhi * 8];
#pragma unroll
      for (int ni = 0; ni < NFN; ++ni)
        b[ni] = *(const bhalf8*)&Bs[(wn * (BN / 2) + ni * 16 + l16) * 64 +
                                    ks * 32 + lhi * 8];
#pragma unroll
      for (int mi = 0; mi < NFM; ++mi)
#pragma unroll
        for (int ni = 0; ni < NFN; ++ni)
          acc[mi][ni] = __builtin_amdgcn_mfma_f32_16x16x32_bf16(
              a[mi], b[ni], acc[mi][ni], 0, 0, 0);
    }
    __syncthreads();
  }

#pragma unroll
  for (int mi = 0; mi < NFM; ++mi) {
#pragma unroll
    for (int ni = 0; ni < NFN; ++ni) {
      const int col = bn + wn * (BN / 2) + ni * 16 + l16;
      float bv;
      if (MODE == 4)
        bv = col < 512 ? bias[col]
                       : (col < 1024 ? bias2[col - 512] : bias3[col - 1024]);
      else
        bv = bias[col];
#pragma unroll
      for (int r = 0; r < 4; ++r) {
        const int row = bm + wm * (BM / 2) + mi * 16 + lhi * 4 + r;
        float v = acc[mi][ni][r] + bv;
        const size_t off = (size_t)row * N + col;
        if (MODE == 0) {
          Cb[off] = f2b(fmaxf(v, 0.0f));
        } else if (MODE == 4) {
          Cb[off] = f2b(v);
        } else {
          if (MODE == 1) v = res[off] + 0.5f * v;
          if (MODE == 3) v = res[off] + v;
          C[off] = v;
        }
      }
    }
  }
}

// ---------------------------------------------------------------------------
// bmm: Sc16[bh][t][s] = bf16( q . pos_k[t,s,:] ); PASS=1 also writes the
// pos_k passthrough copy. q from qkv buffer (row stride QS=1536).
// ---------------------------------------------------------------------------
template <int PASS>
__global__ __launch_bounds__(256) void bmm_kernel(const ushort* __restrict__ qkv,
                                                  const float* __restrict__ pk,
                                                  ushort* __restrict__ Sc16,
                                                  float* __restrict__ pkout) {
  const int s0 = blockIdx.x * 256;
  const int t = blockIdx.y;
  const int tid = threadIdx.x, wid = tid >> 6, l = tid & 63;
  const int l16 = l & 15, lhi = l >> 4;

  __shared__ ushort Qs[32 * 64];
  __shared__ ushort Ps[256 * 64];  // pos_k staging; reused for output transpose

  {
    int row = tid >> 3, c8 = tid & 7;
    int bq = row >> 3, hq = row & 7;
    *(uint4*)&Qs[row * 64 + c8 * 8] = *(const uint4*)(
        qkv + ((size_t)(bq * Tn + t)) * QS + hq * 64 + c8 * 8);
  }
#pragma unroll
  for (int i = 0; i < 16; ++i) {
    int slot = tid + i * 256;
    int sr = slot >> 4, c4 = slot & 15;
    const size_t goff = ((size_t)t * Tn + s0 + sr) * Dk + c4 * 4;
    const float4 p = *(const float4*)(pk + goff);
    if (PASS) *(float4*)(pkout + goff) = p;
    ushort4 u;
    u.x = f2b(p.x);
    u.y = f2b(p.y);
    u.z = f2b(p.z);
    u.w = f2b(p.w);
    *(ushort4*)&Ps[sr * 64 + c4 * 4] = u;
  }
  __syncthreads();

  f4 acc[2][4] = {};
#pragma unroll
  for (int ks = 0; ks < 2; ++ks) {
    bhalf8 a[2], b[4];
#pragma unroll
    for (int mi = 0; mi < 2; ++mi)
      a[mi] = *(const bhalf8*)&Qs[(mi * 16 + l16) * 64 + ks * 32 + lhi * 8];
#pragma unroll
    for (int ni = 0; ni < 4; ++ni)
      b[ni] = *(const bhalf8*)&Ps[(wid * 64 + ni * 16 + l16) * 64 + ks * 32 +
                                  lhi * 8];
#pragma unroll
    for (int mi = 0; mi < 2; ++mi)
#pragma unroll
      for (int ni = 0; ni < 4; ++ni)
        acc[mi][ni] = __builtin_amdgcn_mfma_f32_16x16x32_bf16(
            a[mi], b[ni], acc[mi][ni], 0, 0, 0);
  }

  __syncthreads();  // all waves done reading Ps (pos_k staging)
#pragma unroll
  for (int mi = 0; mi < 2; ++mi)
#pragma unroll
    for (int ni = 0; ni < 4; ++ni)
#pragma unroll
      for (int r = 0; r < 4; ++r) {
        const int bh = mi * 16 + lhi * 4 + r;
        const int sl = wid * 64 + ni * 16 + l16;
        Ps[bh * 256 + sl] = f2b(acc[mi][ni][r]);
      }
  __syncthreads();
#pragma unroll
  for (int i = 0; i < 4; ++i) {
    int idx = tid + i * 256;
    int bh = idx >> 5, sc = (idx & 31) * 8;
    *(uint4*)&Sc16[((size_t)bh * Tn + t) * Tn + s0 + sc] =
        *(const uint4*)&Ps[bh * 256 + sc];
  }
}

// ---------------------------------------------------------------------------
// fattn: flash attention, t-tile = 64 (grid 512 -> 4 blocks/CU, 16 waves/CU).
// q/k/v from qkv buffer (stride QS; k at +512, v at +1024). Bm tile staged
// into Ps via gload16 with both-sides XOR swizzle.
// ---------------------------------------------------------------------------
__global__ __launch_bounds__(256) void fattn_kernel(
    const ushort* __restrict__ qkv, const ushort* __restrict__ Sc16,
    const uint* __restrict__ mbits, ushort* __restrict__ ctxb) {
  const int bh = blockIdx.y;
  const int b = bh >> 3, h = bh & 7;
  const int t0 = blockIdx.x * 64;
  const int tid = threadIdx.x;
  const int wid = tid >> 6, l = tid & 63;
  const int l16 = l & 15, lhi = l >> 4;

  __shared__ ushort KV[8448];      // K [128][64] (8192) / V^T [64][132] (8448)
  __shared__ ushort Ps[64 * 128];  // Bm stage -> P (swizzled); also Q staging

  // Q fragments -> registers (staged via Ps); wave owns rows wid*16..+16
  bhalf8 qa[2];
  {
#pragma unroll
    for (int i = 0; i < 2; ++i) {
      int slot = tid + i * 256;
      int row = slot >> 3, c8 = slot & 7;
      gload16(qkv + ((size_t)(b * Tn + t0 + row)) * QS + h * 64 + c8 * 8,
              &Ps[slot * 8]);
    }
    __syncthreads();
#pragma unroll
    for (int ks = 0; ks < 2; ++ks)
      qa[ks] = *(const bhalf8*)&Ps[(wid * 16 + l16) * 64 + ks * 32 + lhi * 8];
    __syncthreads();
  }

  f4 oacc[4] = {};
  float mrow[4], lrow[4];
#pragma unroll
  for (int r = 0; r < 4; ++r) {
    mrow[r] = -3.0e38f;
    lrow[r] = 0.0f;
  }

  const float scale = 0.125f;
  for (int s0 = 0; s0 < Tn; s0 += 128) {
    // stage K [128 s][64 dk]
#pragma unroll
    for (int i = 0; i < 4; ++i) {
      int slot = tid + i * 256;
      int row = slot >> 3, c8 = slot & 7;
      gload16(qkv + ((size_t)(b * Tn + s0 + row)) * QS + 512 + h * 64 + c8 * 8,
              &KV[slot * 8]);
    }
    // stage Bm tile [64 t][128 s] u16 into Ps, source pre-swizzled (rule #21)
#pragma unroll
    for (int i = 0; i < 4; ++i) {
      int slot = tid + i * 256;            // 1024 slots x 16 B
      int row = slot >> 4, c16 = slot & 15;
      int cb = (c16 * 16) ^ ((row & 7) << 4);
      gload16(
          (const char*)(Sc16 + ((size_t)bh * Tn + t0 + row) * Tn + s0) + cb,
          (char*)Ps + slot * 16);
    }
    __syncthreads();  // K + Bm visible

    // acc init = Bm from LDS (swizzled read)
    f4 accs[8];
#pragma unroll
    for (int r = 0; r < 4; ++r) {
      const int lr = wid * 16 + lhi * 4 + r;
#pragma unroll
      for (int ni = 0; ni < 8; ++ni) {
        const int cb = ((ni * 16 + l16) * 2) ^ ((lr & 7) << 4);
        accs[ni][r] = b2f(*(const ushort*)((const char*)Ps + lr * 256 + cb));
      }
    }

    // QK^T
#pragma unroll
    for (int ks = 0; ks < 2; ++ks) {
      bhalf8 bb[8];
#pragma unroll
      for (int ni = 0; ni < 8; ++ni)
        bb[ni] = *(const bhalf8*)&KV[(ni * 16 + l16) * 64 + ks * 32 + lhi * 8];
#pragma unroll
      for (int ni = 0; ni < 8; ++ni)
        accs[ni] = __builtin_amdgcn_mfma_f32_16x16x32_bf16(qa[ks], bb[ni],
                                                           accs[ni], 0, 0, 0);
    }

    // online softmax (in regs) + P write into Ps (same swizzle; own rows only)
#pragma unroll
    for (int r = 0; r < 4; ++r) {
      const int trow = t0 + wid * 16 + lhi * 4 + r;
      const uint* mw = mbits + ((size_t)b * Tn + trow) * 32 + (s0 >> 5);
      const uint w[4] = {mw[0], mw[1], mw[2], mw[3]};
      float p[8];
      float rm = -3.0e38f;
#pragma unroll
      for (int ni = 0; ni < 8; ++ni) {
        float v = accs[ni][r] * scale;
        const uint bit = (w[ni >> 1] >> ((ni & 1) * 16 + l16)) & 1u;
        v = bit ? v : -3.0e38f;
        p[ni] = v;
        rm = fmaxf(rm, v);
      }
#pragma unroll
      for (int off = 8; off; off >>= 1) rm = fmaxf(rm, __shfl_xor(rm, off));
      const float mnew = fmaxf(mrow[r], rm);
      const float sold = __expf(mrow[r] - mnew);
      mrow[r] = mnew;
      float rs = 0.0f;
#pragma unroll
      for (int ni = 0; ni < 8; ++ni) {
        const float e = __expf(p[ni] - mnew);
        rs += e;
        p[ni] = e;
      }
#pragma unroll
      for (int off = 8; off; off >>= 1) rs += __shfl_xor(rs, off);
      lrow[r] = lrow[r] * sold + rs;
#pragma unroll
      for (int ni = 0; ni < 4; ++ni) oacc[ni][r] *= sold;
      const int lr = wid * 16 + lhi * 4 + r;
#pragma unroll
      for (int ni = 0; ni < 8; ++ni) {
        const int byte = (lr * 256 + (((ni * 16 + l16) * 2) ^ ((lr & 7) << 4)));
        *(ushort*)((char*)Ps + byte) = f2b(p[ni]);
      }
    }
    __syncthreads();  // QK done reading KV; P written

    // stage V^T [64 d][132 stride], all 128 s rows
#pragma unroll
    for (int i = 0; i < 4; ++i) {
      int slot = tid + i * 256;
      int sr = slot >> 3, c8 = slot & 7;
      const uint4 raw = *(const uint4*)(
          qkv + ((size_t)(b * Tn + s0 + sr)) * QS + 1024 + h * 64 + c8 * 8);
      const ushort* e = (const ushort*)&raw;
#pragma unroll
      for (int j = 0; j < 8; ++j) KV[(c8 * 8 + j) * 132 + sr] = e[j];
    }
    __syncthreads();  // V^T + P visible

    // PV (P read with matching swizzle)
#pragma unroll
    for (int ks = 0; ks < 4; ++ks) {
      bhalf8 a, bb[4];
      {
        const int lr = wid * 16 + l16;
        const int byte = (lr * 256 + ((ks * 64 + lhi * 16) ^ ((lr & 7) << 4)));
        a = *(const bhalf8*)((char*)Ps + byte);
      }
#pragma unroll
      for (int ni = 0; ni < 4; ++ni)
        bb[ni] = *(const bhalf8*)&KV[(ni * 16 + l16) * 132 + ks * 32 + lhi * 8];
#pragma unroll
      for (int ni = 0; ni < 4; ++ni)
        oacc[ni] = __builtin_amdgcn_mfma_f32_16x16x32_bf16(a, bb[ni], oacc[ni],
                                                           0, 0, 0);
    }
    __syncthreads();  // protect KV/Ps for next iter
  }

#pragma unroll
  for (int r = 0; r < 4; ++r) {
    const float inv =
        (mrow[r] <= -1.0e37f) ? 0.0f : 1.0f / fmaxf(lrow[r], 1e-30f);
    const int t = t0 + wid * 16 + lhi * 4 + r;
#pragma unroll
    for (int ni = 0; ni < 4; ++ni) {
      const int d = ni * 16 + l16;
      ctxb[((size_t)(b * Tn + t)) * Dn + h * 64 + d] = f2b(oacc[ni][r] * inv);
    }
  }
}

// ---------------------------------------------------------------------------
// conv2: depthwise conv1d (K=31) + ReLU + pw2 + residual; register window.
// ---------------------------------------------------------------------------
__global__ __launch_bounds__(256) void conv2_kernel(
    const float* __restrict__ y, const float* __restrict__ dww,
    const float* __restrict__ dwb, const float* __restrict__ pw2w,
    const float* __restrict__ pw2b, float* __restrict__ x) {
  const int b = blockIdx.z;
  const int d0 = blockIdx.y * 256;
  const int t0 = blockIdx.x * 16;
  const int tid = threadIdx.x;
  const int d = d0 + tid;

  __shared__ float wlds[256 * Kw];
#pragma unroll
  for (int i = 0; i < Kw; ++i)
    wlds[i * 256 + tid] = dww[(size_t)d0 * Kw + i * 256 + tid];
  __syncthreads();

  float w[Kw];
#pragma unroll
  for (int k = 0; k < Kw; ++k) w[k] = wlds[tid * Kw + k];

  float v[46];
#pragma unroll
  for (int i = 0; i < 46; ++i) {
    int t = t0 - 15 + i;
    v[i] = (t >= 0 && t < Tn) ? y[((size_t)b * Tn + t) * Dn + d] : 0.0f;
  }

  const float bias = dwb[d], w2 = pw2w[0], c2 = pw2b[0];
#pragma unroll
  for (int j = 0; j < 16; ++j) {
    float acc = bias;
#pragma unroll
    for (int k = 0; k < Kw; ++k) acc += w[k] * v[j + k];
    acc = fmaxf(acc, 0.0f);
    const size_t idx = ((size_t)b * Tn + t0 + j) * Dn + d;
    x[idx] = x[idx] + w2 * acc + c2;
  }
}

// ---------------------------------------------------------------------------
// maskcvt: int32 mask -> fp32 passthrough output AND packed bits (1 bit/s).
// ---------------------------------------------------------------------------
__global__ __launch_bounds__(256) void maskcvt_kernel(
    const int* __restrict__ in, float* __restrict__ outf,
    uint* __restrict__ mbits) {
  const size_t idx = (size_t)blockIdx.x * 256 + threadIdx.x;
  const size_t base = idx * 32;
  uint bits = 0;
#pragma unroll
  for (int j = 0; j < 8; ++j) {
    const int4 v = *(const int4*)(in + base + j * 4);
    float4 f;
    f.x = (float)v.x;
    f.y = (float)v.y;
    f.z = (float)v.z;
    f.w = (float)v.w;
    *(float4*)(outf + base + j * 4) = f;
    bits |= (v.x != 0 ? 1u : 0u) << (j * 4 + 0);
    bits |= (v.y != 0 ? 1u : 0u) << (j * 4 + 1);
    bits |= (v.z != 0 ? 1u : 0u) << (j * 4 + 2);
    bits |= (v.w != 0 ? 1u : 0u) << (j * 4 + 3);
  }
  mbits[idx] = bits;
}

// ---------------------------------------------------------------------------
extern "C" void kernel_launch(void* const* d_in, const int* in_sizes, int n_in,
                              void* d_out, int out_size, void* d_ws,
                              size_t ws_size, hipStream_t stream) {
  const float* x = (const float*)d_in[0];
  const float* pos_k = (const float*)d_in[1];
  const int* mask = (const int*)d_in[2];
  const float* fi_g = (const float*)d_in[3];
  const float* fi_b = (const float*)d_in[4];
  const float* fi_w1 = (const float*)d_in[5];
  const float* fi_b1 = (const float*)d_in[6];
  const float* fi_w2 = (const float*)d_in[7];
  const float* fi_b2 = (const float*)d_in[8];
  const float* at_g = (const float*)d_in[9];
  const float* at_b = (const float*)d_in[10];
  const float* wq = (const float*)d_in[11];
  const float* bq = (const float*)d_in[12];
  const float* wk = (const float*)d_in[13];
  const float* bk = (const float*)d_in[14];
  const float* wv = (const float*)d_in[15];
  const float* bv = (const float*)d_in[16];
  const float* wo = (const float*)d_in[17];
  const float* bo = (const float*)d_in[18];
  const float* cv_g = (const float*)d_in[19];
  const float* cv_b = (const float*)d_in[20];
  const float* pw1w = (const float*)d_in[21];
  const float* pw1b = (const float*)d_in[22];
  const float* dww = (const float*)d_in[23];
  const float* dwb = (const float*)d_in[24];
  const float* pw2w = (const float*)d_in[25];
  const float* pw2b = (const float*)d_in[26];
  const float* fo_g = (const float*)d_in[27];
  const float* fo_b = (const float*)d_in[28];
  const float* fo_w1 = (const float*)d_in[29];
  const float* fo_b1 = (const float*)d_in[30];
  const float* fo_w2 = (const float*)d_in[31];
  const float* fo_b2 = (const float*)d_in[32];
  const float* fl_g = (const float*)d_in[33];
  const float* fl_b = (const float*)d_in[34];

  float* out = (float*)d_out;

  // ws front: xcur | y | mbits (always)
  float* xcur = (float*)d_ws;
  float* y = xcur + N_OUT;
  uint* mbits = (uint*)(y + N_OUT);  // 512 KB

  // big scratch: prefer ws (enables fused pos_k passthrough); else out region
  const size_t NEED = (size_t)206 << 20;
  const bool fused = ws_size >= NEED;
  char* sp = fused ? (char*)(mbits + N_MASK / 32) : (char*)(out + N_OUT);
  auto alloc16 = [&](size_t elems) {
    ushort* p = (ushort*)sp;
    sp += ((elems * 2 + 255) & ~(size_t)255);
    return p;
  };
  ushort* Sc16 = alloc16((size_t)32 * Tn * Tn);  // 67 MB
  ushort* wt_fi1 = alloc16((size_t)Fn * Dn);
  ushort* wt_fi2 = alloc16((size_t)Dn * Fn);
  ushort* wt_qkv = alloc16((size_t)QS * Dn);  // [1536][512]
  ushort* wt_o = alloc16((size_t)Dn * Dn);
  ushort* wt_fo1 = alloc16((size_t)Fn * Dn);
  ushort* wt_fo2 = alloc16((size_t)Dn * Fn);
  ushort* ybf = alloc16(N_OUT);
  ushort* hbf = alloc16((size_t)Bsz * Tn * Fn);
  ushort* ctxbf = alloc16(N_OUT);
  ushort* qkvbf = alloc16((size_t)Bsz * Tn * QS);  // 25 MB

  const int M = Bsz * Tn;  // 4096
  const dim3 blk256(256);
  const dim3 grid_rows(M);
  const dim3 gF(Fn / 128, M / 128);    // 128x128, N=2048
  const dim3 gD64(Dn / 64, M / 64);    // 64x64,  N=512: 512 blocks
  const dim3 gQKV(QS / 64, M / 128);   // 128x64, N=1536

  // mask passthrough + bit-pack (early; flash needs mbits)
  maskcvt_kernel<<<dim3(N_MASK / 32 / 256), blk256, 0, stream>>>(
      mask, out + N_OUT + N_POSK, mbits);

  // all weight conversions in one launch
  wcvt8_kernel<<<dim3(5120), blk256, 0, stream>>>(
      fi_w1, fi_w2, wq, wk, wv, wo, fo_w1, fo_w2, wt_fi1, wt_fi2, wt_qkv,
      wt_qkv + (size_t)Dn * Dn, wt_qkv + (size_t)2 * Dn * Dn, wt_o, wt_fo1,
      wt_fo2);

  // macaron FFN-in (first LN reads x directly; MODE 1 res=x writes xcur)
  ln_kernel<0, 1><<<grid_rows, blk256, 0, stream>>>(x, fi_g, fi_b, nullptr,
                                                    ybf, nullptr, nullptr);
  mgemm_kernel<0, 128, 128><<<gF, blk256, 0, stream>>>(
      ybf, wt_fi1, fi_b1, nullptr, nullptr, nullptr, nullptr, hbf, M, Fn, Dn);
  mgemm_kernel<1, 64, 64><<<gD64, blk256, 0, stream>>>(
      hbf, wt_fi2, fi_b2, nullptr, nullptr, x, xcur, nullptr, M, Dn, Fn);

  // attention: fused QKV projection (N=1536)
  ln_kernel<0, 1><<<grid_rows, blk256, 0, stream>>>(xcur, at_g, at_b, nullptr,
                                                    ybf, nullptr, nullptr);
  mgemm_kernel<4, 128, 64><<<gQKV, blk256, 0, stream>>>(
      ybf, wt_qkv, bq, bk, bv, nullptr, nullptr, qkvbf, M, QS, Dn);

  if (fused)
    bmm_kernel<1><<<dim3(4, Tn), blk256, 0, stream>>>(qkvbf, pos_k, Sc16,
                                                      out + N_OUT);
  else
    bmm_kernel<0><<<dim3(4, Tn), blk256, 0, stream>>>(qkvbf, pos_k, Sc16,
                                                      nullptr);

  fattn_kernel<<<dim3(Tn / 64, 32), blk256, 0, stream>>>(qkvbf, Sc16, mbits,
                                                         ctxbf);

  mgemm_kernel<3, 64, 64><<<gD64, blk256, 0, stream>>>(
      ctxbf, wt_o, bo, nullptr, nullptr, xcur, xcur, nullptr, M, Dn, Dn);

  // conv module
  ln_kernel<1, 0><<<grid_rows, blk256, 0, stream>>>(xcur, cv_g, cv_b, y,
                                                    nullptr, pw1w, pw1b);
  conv2_kernel<<<dim3(Tn / 16, 2, Bsz), blk256, 0, stream>>>(y, dww, dwb, pw2w,
                                                             pw2b, xcur);

  // macaron FFN-out
  ln_kernel<0, 1><<<grid_rows, blk256, 0, stream>>>(xcur, fo_g, fo_b, nullptr,
                                                    ybf, nullptr, nullptr);
  mgemm_kernel<0, 128, 128><<<gF, blk256, 0, stream>>>(
      ybf, wt_fo1, fo_b1, nullptr, nullptr, nullptr, nullptr, hbf, M, Fn, Dn);
  mgemm_kernel<1, 64, 64><<<gD64, blk256, 0, stream>>>(
      hbf, wt_fo2, fo_b2, nullptr, nullptr, xcur, xcur, nullptr, M, Dn, Fn);

  // final LN -> d_out[0]
  ln_kernel<0, 0><<<grid_rows, blk256, 0, stream>>>(xcur, fl_g, fl_b, out,
                                                    nullptr, nullptr, nullptr);

  // pos_k passthrough (only if not fused into bmm)
  if (!fused)
    hipMemcpyAsync(out + N_OUT, pos_k, N_POSK * sizeof(float),
                   hipMemcpyDeviceToDevice, stream);
}

// Round 11
// 360.267 us; speedup vs baseline: 1.1621x; 1.0098x over previous
//
#include <hip/hip_runtime.h>
#include <math.h>

static constexpr int Bsz = 4, Tn = 1024, Dn = 512, Hn = 8, Fn = 2048, Kw = 31, Dk = 64;
static constexpr int QS = 3 * Dn;  // 1536, qkv row stride
static constexpr size_t N_OUT  = (size_t)Bsz * Tn * Dn;   // 2,097,152
static constexpr size_t N_POSK = (size_t)Tn * Tn * Dk;    // 67,108,864
static constexpr size_t N_MASK = (size_t)Bsz * Tn * Tn;   // 4,194,304

typedef __attribute__((ext_vector_type(8))) short bhalf8;  // 8 bf16 (4 VGPR)
typedef __attribute__((ext_vector_type(4))) float f4;      // MFMA C/D

__device__ __forceinline__ ushort f2b(float f) {
  uint b = __float_as_uint(f);
  uint r = (b + 0x7FFFu + ((b >> 16) & 1u)) >> 16;
  return (ushort)r;
}
__device__ __forceinline__ float b2f(ushort u) {
  return __uint_as_float((uint)u << 16);
}

// async global->LDS, 16 B per lane
typedef const __attribute__((address_space(1))) unsigned int* gp1_t;
typedef __attribute__((address_space(3))) unsigned int* lp3_t;
__device__ __forceinline__ void gload16(const void* g, void* l) {
  __builtin_amdgcn_global_load_lds((gp1_t)g, (lp3_t)l, 16, 0, 0);
}

// ---------------------------------------------------------------------------
// LayerNorm; BF=1 -> bf16 output, BF=0 -> fp32 output. GLU on fp32 path.
// ---------------------------------------------------------------------------
template <int GLU, int BF>
__global__ __launch_bounds__(256) void ln_kernel(
    const float* __restrict__ x, const float* __restrict__ g,
    const float* __restrict__ b, float* __restrict__ yf,
    ushort* __restrict__ yb, const float* __restrict__ pw1w,
    const float* __restrict__ pw1b) {
  const int row = blockIdx.x;
  const float* xr = x + (size_t)row * Dn;
  const int tid = threadIdx.x, wid = tid >> 6, lane = tid & 63;

  __shared__ float red[4];
  __shared__ float bc[2];

  float v0 = xr[tid], v1 = xr[tid + 256];
  float s = v0 + v1;
#pragma unroll
  for (int off = 32; off; off >>= 1) s += __shfl_xor(s, off);
  if (lane == 0) red[wid] = s;
  __syncthreads();
  if (tid == 0) bc[0] = (red[0] + red[1] + red[2] + red[3]) * (1.0f / Dn);
  __syncthreads();
  const float m = bc[0];
  const float d0 = v0 - m, d1 = v1 - m;
  float s2 = d0 * d0 + d1 * d1;
#pragma unroll
  for (int off = 32; off; off >>= 1) s2 += __shfl_xor(s2, off);
  if (lane == 0) red[wid] = s2;
  __syncthreads();
  if (tid == 0)
    bc[1] = rsqrtf((red[0] + red[1] + red[2] + red[3]) * (1.0f / Dn) + 1e-5f);
  __syncthreads();
  const float r = bc[1];

  float o0 = d0 * r * g[tid] + b[tid];
  float o1 = d1 * r * g[tid + 256] + b[tid + 256];
  if (GLU) {
    const float w0 = pw1w[0], w1 = pw1w[1], c0 = pw1b[0], c1 = pw1b[1];
    o0 = (w0 * o0 + c0) * (1.0f / (1.0f + expf(-(w1 * o0 + c1))));
    o1 = (w0 * o1 + c0) * (1.0f / (1.0f + expf(-(w1 * o1 + c1))));
  }
  if (BF) {
    yb[(size_t)row * Dn + tid] = f2b(o0);
    yb[(size_t)row * Dn + tid + 256] = f2b(o1);
  } else {
    yf[(size_t)row * Dn + tid] = o0;
    yf[(size_t)row * Dn + tid + 256] = o1;
  }
}

// ---------------------------------------------------------------------------
// prep: blocks [0,512) = mask passthrough + bit-pack; [512, 5632) = the 8
// weight transposes/converts (32x32 tiles).
// ---------------------------------------------------------------------------
__global__ __launch_bounds__(256) void prep_kernel(
    const int* __restrict__ maskin, float* __restrict__ maskoutf,
    uint* __restrict__ mbits, const float* s0, const float* s1,
    const float* s2, const float* s3, const float* s4, const float* s5,
    const float* s6, const float* s7, ushort* d0, ushort* d1, ushort* d2,
    ushort* d3, ushort* d4, ushort* d5, ushort* d6, ushort* d7) {
  int bid = blockIdx.x;
  if (bid < 512) {
    const size_t idx = (size_t)bid * 256 + threadIdx.x;
    const size_t base = idx * 32;
    uint bits = 0;
#pragma unroll
    for (int j = 0; j < 8; ++j) {
      const int4 v = *(const int4*)(maskin + base + j * 4);
      float4 f;
      f.x = (float)v.x;
      f.y = (float)v.y;
      f.z = (float)v.z;
      f.w = (float)v.w;
      *(float4*)(maskoutf + base + j * 4) = f;
      bits |= (v.x != 0 ? 1u : 0u) << (j * 4 + 0);
      bits |= (v.y != 0 ? 1u : 0u) << (j * 4 + 1);
      bits |= (v.z != 0 ? 1u : 0u) << (j * 4 + 2);
      bits |= (v.w != 0 ? 1u : 0u) << (j * 4 + 3);
    }
    mbits[idx] = bits;
    return;
  }
  bid -= 512;
  const float* W;
  ushort* Wt;
  int K, N, tile;
  if (bid < 1024)      { W = s0; Wt = d0; K = Dn; N = Fn; tile = bid; }
  else if (bid < 2048) { W = s1; Wt = d1; K = Fn; N = Dn; tile = bid - 1024; }
  else if (bid < 2304) { W = s2; Wt = d2; K = Dn; N = Dn; tile = bid - 2048; }
  else if (bid < 2560) { W = s3; Wt = d3; K = Dn; N = Dn; tile = bid - 2304; }
  else if (bid < 2816) { W = s4; Wt = d4; K = Dn; N = Dn; tile = bid - 2560; }
  else if (bid < 3072) { W = s5; Wt = d5; K = Dn; N = Dn; tile = bid - 2816; }
  else if (bid < 4096) { W = s6; Wt = d6; K = Dn; N = Fn; tile = bid - 3072; }
  else                 { W = s7; Wt = d7; K = Fn; N = Dn; tile = bid - 4096; }
  const int nt = N / 32;
  const int n0 = (tile % nt) * 32, k0 = (tile / nt) * 32;

  __shared__ float tilebuf[32][33];
  const int tx = threadIdx.x & 31, ty = threadIdx.x >> 5;
#pragma unroll
  for (int i = 0; i < 4; ++i) {
    int k = ty + i * 8;
    tilebuf[k][tx] = W[(size_t)(k0 + k) * N + n0 + tx];
  }
  __syncthreads();
#pragma unroll
  for (int i = 0; i < 4; ++i) {
    int r = ty + i * 8;
    Wt[(size_t)(n0 + r) * K + k0 + tx] = f2b(tilebuf[tx][r]);
  }
}

// ---------------------------------------------------------------------------
// bf16 MFMA GEMM (NT), tile BM x BN, 4 waves (2x2), wave tile BM/2 x BN/2.
// MODE 0: relu -> bf16 Cb     MODE 1: C = res + 0.5*v (fp32)
// MODE 3: C = res + v (fp32)  MODE 4: Cb = bf16(v), 3-segment bias (QKV)
// ---------------------------------------------------------------------------
template <int MODE, int BM, int BN>
__global__ __launch_bounds__(256) void mgemm_kernel(
    const ushort* __restrict__ A, const ushort* __restrict__ Bt,
    const float* __restrict__ bias, const float* __restrict__ bias2,
    const float* __restrict__ bias3, const float* __restrict__ res,
    float* __restrict__ C, ushort* __restrict__ Cb, int M, int N, int K) {
  constexpr int NFM = BM / 32;
  constexpr int NFN = BN / 32;
  __shared__ ushort As[BM * 64];
  __shared__ ushort Bs[BN * 64];
  const int bm = blockIdx.y * BM, bn = blockIdx.x * BN;
  const int tid = threadIdx.x;
  const int wid = tid >> 6, l = tid & 63;
  const int wm = wid >> 1, wn = wid & 1;
  const int l16 = l & 15, lhi = l >> 4;

  f4 acc[NFM][NFN] = {};

  for (int k0 = 0; k0 < K; k0 += 64) {
#pragma unroll
    for (int i = 0; i < BM * 8 / 256; ++i) {
      int slot = tid + i * 256;
      int row = slot >> 3, c8 = slot & 7;
      gload16(A + (size_t)(bm + row) * K + k0 + c8 * 8, &As[slot * 8]);
    }
#pragma unroll
    for (int i = 0; i < BN * 8 / 256; ++i) {
      int slot = tid + i * 256;
      int row = slot >> 3, c8 = slot & 7;
      gload16(Bt + (size_t)(bn + row) * K + k0 + c8 * 8, &Bs[slot * 8]);
    }
    __syncthreads();
#pragma unroll
    for (int ks = 0; ks < 2; ++ks) {
      bhalf8 a[NFM], b[NFN];
#pragma unroll
      for (int mi = 0; mi < NFM; ++mi)
        a[mi] = *(const bhalf8*)&As[(wm * (BM / 2) + mi * 16 + l16) * 64 +
                                    ks * 32 + lhi * 8];
#pragma unroll
      for (int ni = 0; ni < NFN; ++ni)
        b[ni] = *(const bhalf8*)&Bs[(wn * (BN / 2) + ni * 16 + l16) * 64 +
                                    ks * 32 + lhi * 8];
#pragma unroll
      for (int mi = 0; mi < NFM; ++mi)
#pragma unroll
        for (int ni = 0; ni < NFN; ++ni)
          acc[mi][ni] = __builtin_amdgcn_mfma_f32_16x16x32_bf16(
              a[mi], b[ni], acc[mi][ni], 0, 0, 0);
    }
    __syncthreads();
  }

#pragma unroll
  for (int mi = 0; mi < NFM; ++mi) {
#pragma unroll
    for (int ni = 0; ni < NFN; ++ni) {
      const int col = bn + wn * (BN / 2) + ni * 16 + l16;
      float bv;
      if (MODE == 4)
        bv = col < 512 ? bias[col]
                       : (col < 1024 ? bias2[col - 512] : bias3[col - 1024]);
      else
        bv = bias[col];
#pragma unroll
      for (int r = 0; r < 4; ++r) {
        const int row = bm + wm * (BM / 2) + mi * 16 + lhi * 4 + r;
        float v = acc[mi][ni][r] + bv;
        const size_t off = (size_t)row * N + col;
        if (MODE == 0) {
          Cb[off] = f2b(fmaxf(v, 0.0f));
        } else if (MODE == 4) {
          Cb[off] = f2b(v);
        } else {
          if (MODE == 1) v = res[off] + 0.5f * v;
          if (MODE == 3) v = res[off] + v;
          C[off] = v;
        }
      }
    }
  }
}

// ---------------------------------------------------------------------------
// bmm: Sc16[bh][t][s] = bf16( q . pos_k[t,s,:] ); PASS=1 also writes the
// pos_k passthrough copy. q from qkv buffer (row stride QS=1536).
// ---------------------------------------------------------------------------
template <int PASS>
__global__ __launch_bounds__(256) void bmm_kernel(const ushort* __restrict__ qkv,
                                                  const float* __restrict__ pk,
                                                  ushort* __restrict__ Sc16,
                                                  float* __restrict__ pkout) {
  const int s0 = blockIdx.x * 256;
  const int t = blockIdx.y;
  const int tid = threadIdx.x, wid = tid >> 6, l = tid & 63;
  const int l16 = l & 15, lhi = l >> 4;

  __shared__ ushort Qs[32 * 64];
  __shared__ ushort Ps[256 * 64];  // pos_k staging; reused for output transpose

  {
    int row = tid >> 3, c8 = tid & 7;
    int bq = row >> 3, hq = row & 7;
    *(uint4*)&Qs[row * 64 + c8 * 8] = *(const uint4*)(
        qkv + ((size_t)(bq * Tn + t)) * QS + hq * 64 + c8 * 8);
  }
#pragma unroll
  for (int i = 0; i < 16; ++i) {
    int slot = tid + i * 256;
    int sr = slot >> 4, c4 = slot & 15;
    const size_t goff = ((size_t)t * Tn + s0 + sr) * Dk + c4 * 4;
    const float4 p = *(const float4*)(pk + goff);
    if (PASS) *(float4*)(pkout + goff) = p;
    ushort4 u;
    u.x = f2b(p.x);
    u.y = f2b(p.y);
    u.z = f2b(p.z);
    u.w = f2b(p.w);
    *(ushort4*)&Ps[sr * 64 + c4 * 4] = u;
  }
  __syncthreads();

  f4 acc[2][4] = {};
#pragma unroll
  for (int ks = 0; ks < 2; ++ks) {
    bhalf8 a[2], b[4];
#pragma unroll
    for (int mi = 0; mi < 2; ++mi)
      a[mi] = *(const bhalf8*)&Qs[(mi * 16 + l16) * 64 + ks * 32 + lhi * 8];
#pragma unroll
    for (int ni = 0; ni < 4; ++ni)
      b[ni] = *(const bhalf8*)&Ps[(wid * 64 + ni * 16 + l16) * 64 + ks * 32 +
                                  lhi * 8];
#pragma unroll
    for (int mi = 0; mi < 2; ++mi)
#pragma unroll
      for (int ni = 0; ni < 4; ++ni)
        acc[mi][ni] = __builtin_amdgcn_mfma_f32_16x16x32_bf16(
            a[mi], b[ni], acc[mi][ni], 0, 0, 0);
  }

  __syncthreads();  // all waves done reading Ps (pos_k staging)
#pragma unroll
  for (int mi = 0; mi < 2; ++mi)
#pragma unroll
    for (int ni = 0; ni < 4; ++ni)
#pragma unroll
      for (int r = 0; r < 4; ++r) {
        const int bh = mi * 16 + lhi * 4 + r;
        const int sl = wid * 64 + ni * 16 + l16;
        Ps[bh * 256 + sl] = f2b(acc[mi][ni][r]);
      }
  __syncthreads();
#pragma unroll
  for (int i = 0; i < 4; ++i) {
    int idx = tid + i * 256;
    int bh = idx >> 5, sc = (idx & 31) * 8;
    *(uint4*)&Sc16[((size_t)bh * Tn + t) * Tn + s0 + sc] =
        *(const uint4*)&Ps[bh * 256 + sc];
  }
}

// ---------------------------------------------------------------------------
// fattn: flash attention, t-tile = 64. T14: V global loads issue at loop top
// (overlap with K/Bm gload + QK/softmax), ds_write after P barrier. T5:
// setprio(1) around MFMA clusters.
// ---------------------------------------------------------------------------
__global__ __launch_bounds__(256) void fattn_kernel(
    const ushort* __restrict__ qkv, const ushort* __restrict__ Sc16,
    const uint* __restrict__ mbits, ushort* __restrict__ ctxb) {
  const int bh = blockIdx.y;
  const int b = bh >> 3, h = bh & 7;
  const int t0 = blockIdx.x * 64;
  const int tid = threadIdx.x;
  const int wid = tid >> 6, l = tid & 63;
  const int l16 = l & 15, lhi = l >> 4;

  __shared__ ushort KV[8448];      // K [128][64] (8192) / V^T [64][132] (8448)
  __shared__ ushort Ps[64 * 128];  // Bm stage -> P (swizzled); also Q staging

  // Q fragments -> registers (staged via Ps); wave owns rows wid*16..+16
  bhalf8 qa[2];
  {
#pragma unroll
    for (int i = 0; i < 2; ++i) {
      int slot = tid + i * 256;
      int row = slot >> 3, c8 = slot & 7;
      gload16(qkv + ((size_t)(b * Tn + t0 + row)) * QS + h * 64 + c8 * 8,
              &Ps[slot * 8]);
    }
    __syncthreads();
#pragma unroll
    for (int ks = 0; ks < 2; ++ks)
      qa[ks] = *(const bhalf8*)&Ps[(wid * 16 + l16) * 64 + ks * 32 + lhi * 8];
    __syncthreads();
  }

  f4 oacc[4] = {};
  float mrow[4], lrow[4];
#pragma unroll
  for (int r = 0; r < 4; ++r) {
    mrow[r] = -3.0e38f;
    lrow[r] = 0.0f;
  }

  const float scale = 0.125f;
  for (int s0 = 0; s0 < Tn; s0 += 128) {
    // issue K [128 s][64 dk] gload (async)
#pragma unroll
    for (int i = 0; i < 4; ++i) {
      int slot = tid + i * 256;
      int row = slot >> 3, c8 = slot & 7;
      gload16(qkv + ((size_t)(b * Tn + s0 + row)) * QS + 512 + h * 64 + c8 * 8,
              &KV[slot * 8]);
    }
    // issue Bm tile [64 t][128 s] gload into Ps, source pre-swizzled
#pragma unroll
    for (int i = 0; i < 4; ++i) {
      int slot = tid + i * 256;            // 1024 slots x 16 B
      int row = slot >> 4, c16 = slot & 15;
      int cb = (c16 * 16) ^ ((row & 7) << 4);
      gload16(
          (const char*)(Sc16 + ((size_t)bh * Tn + t0 + row) * Tn + s0) + cb,
          (char*)Ps + slot * 16);
    }
    // T14: issue V reads into regs now (consumed after P barrier)
    uint4 vreg[4];
#pragma unroll
    for (int i = 0; i < 4; ++i) {
      int slot = tid + i * 256;
      int sr = slot >> 3, c8 = slot & 7;
      vreg[i] = *(const uint4*)(qkv + ((size_t)(b * Tn + s0 + sr)) * QS + 1024 +
                                h * 64 + c8 * 8);
    }
    __syncthreads();  // K + Bm visible (drains all loads incl. vreg)

    // acc init = Bm from LDS (swizzled read)
    f4 accs[8];
#pragma unroll
    for (int r = 0; r < 4; ++r) {
      const int lr = wid * 16 + lhi * 4 + r;
#pragma unroll
      for (int ni = 0; ni < 8; ++ni) {
        const int cb = ((ni * 16 + l16) * 2) ^ ((lr & 7) << 4);
        accs[ni][r] = b2f(*(const ushort*)((const char*)Ps + lr * 256 + cb));
      }
    }

    // QK^T
    __builtin_amdgcn_s_setprio(1);
#pragma unroll
    for (int ks = 0; ks < 2; ++ks) {
      bhalf8 bb[8];
#pragma unroll
      for (int ni = 0; ni < 8; ++ni)
        bb[ni] = *(const bhalf8*)&KV[(ni * 16 + l16) * 64 + ks * 32 + lhi * 8];
#pragma unroll
      for (int ni = 0; ni < 8; ++ni)
        accs[ni] = __builtin_amdgcn_mfma_f32_16x16x32_bf16(qa[ks], bb[ni],
                                                           accs[ni], 0, 0, 0);
    }
    __builtin_amdgcn_s_setprio(0);

    // online softmax (in regs) + P write into Ps (same swizzle; own rows only)
#pragma unroll
    for (int r = 0; r < 4; ++r) {
      const int trow = t0 + wid * 16 + lhi * 4 + r;
      const uint* mw = mbits + ((size_t)b * Tn + trow) * 32 + (s0 >> 5);
      const uint w[4] = {mw[0], mw[1], mw[2], mw[3]};
      float p[8];
      float rm = -3.0e38f;
#pragma unroll
      for (int ni = 0; ni < 8; ++ni) {
        float v = accs[ni][r] * scale;
        const uint bit = (w[ni >> 1] >> ((ni & 1) * 16 + l16)) & 1u;
        v = bit ? v : -3.0e38f;
        p[ni] = v;
        rm = fmaxf(rm, v);
      }
#pragma unroll
      for (int off = 8; off; off >>= 1) rm = fmaxf(rm, __shfl_xor(rm, off));
      const float mnew = fmaxf(mrow[r], rm);
      const float sold = __expf(mrow[r] - mnew);
      mrow[r] = mnew;
      float rs = 0.0f;
#pragma unroll
      for (int ni = 0; ni < 8; ++ni) {
        const float e = __expf(p[ni] - mnew);
        rs += e;
        p[ni] = e;
      }
#pragma unroll
      for (int off = 8; off; off >>= 1) rs += __shfl_xor(rs, off);
      lrow[r] = lrow[r] * sold + rs;
#pragma unroll
      for (int ni = 0; ni < 4; ++ni) oacc[ni][r] *= sold;
      const int lr = wid * 16 + lhi * 4 + r;
#pragma unroll
      for (int ni = 0; ni < 8; ++ni) {
        const int byte = (lr * 256 + (((ni * 16 + l16) * 2) ^ ((lr & 7) << 4)));
        *(ushort*)((char*)Ps + byte) = f2b(p[ni]);
      }
    }
    __syncthreads();  // QK done reading KV; P written

    // write V^T [64 d][132 stride] from vreg (T14 write-late)
#pragma unroll
    for (int i = 0; i < 4; ++i) {
      int slot = tid + i * 256;
      int sr = slot >> 3, c8 = slot & 7;
      const ushort* e = (const ushort*)&vreg[i];
#pragma unroll
      for (int j = 0; j < 8; ++j) KV[(c8 * 8 + j) * 132 + sr] = e[j];
    }
    __syncthreads();  // V^T + P visible

    // PV (P read with matching swizzle)
    __builtin_amdgcn_s_setprio(1);
#pragma unroll
    for (int ks = 0; ks < 4; ++ks) {
      bhalf8 a, bb[4];
      {
        const int lr = wid * 16 + l16;
        const int byte = (lr * 256 + ((ks * 64 + lhi * 16) ^ ((lr & 7) << 4)));
        a = *(const bhalf8*)((char*)Ps + byte);
      }
#pragma unroll
      for (int ni = 0; ni < 4; ++ni)
        bb[ni] = *(const bhalf8*)&KV[(ni * 16 + l16) * 132 + ks * 32 + lhi * 8];
#pragma unroll
      for (int ni = 0; ni < 4; ++ni)
        oacc[ni] = __builtin_amdgcn_mfma_f32_16x16x32_bf16(a, bb[ni], oacc[ni],
                                                           0, 0, 0);
    }
    __builtin_amdgcn_s_setprio(0);
    __syncthreads();  // protect KV/Ps for next iter
  }

#pragma unroll
  for (int r = 0; r < 4; ++r) {
    const float inv =
        (mrow[r] <= -1.0e37f) ? 0.0f : 1.0f / fmaxf(lrow[r], 1e-30f);
    const int t = t0 + wid * 16 + lhi * 4 + r;
#pragma unroll
    for (int ni = 0; ni < 4; ++ni) {
      const int d = ni * 16 + l16;
      ctxb[((size_t)(b * Tn + t)) * Dn + h * 64 + d] = f2b(oacc[ni][r] * inv);
    }
  }
}

// ---------------------------------------------------------------------------
// conv2: depthwise conv1d (K=31) + ReLU + pw2 + residual; register window.
// ---------------------------------------------------------------------------
__global__ __launch_bounds__(256) void conv2_kernel(
    const float* __restrict__ y, const float* __restrict__ dww,
    const float* __restrict__ dwb, const float* __restrict__ pw2w,
    const float* __restrict__ pw2b, float* __restrict__ x) {
  const int b = blockIdx.z;
  const int d0 = blockIdx.y * 256;
  const int t0 = blockIdx.x * 16;
  const int tid = threadIdx.x;
  const int d = d0 + tid;

  __shared__ float wlds[256 * Kw];
#pragma unroll
  for (int i = 0; i < Kw; ++i)
    wlds[i * 256 + tid] = dww[(size_t)d0 * Kw + i * 256 + tid];
  __syncthreads();

  float w[Kw];
#pragma unroll
  for (int k = 0; k < Kw; ++k) w[k] = wlds[tid * Kw + k];

  float v[46];
#pragma unroll
  for (int i = 0; i < 46; ++i) {
    int t = t0 - 15 + i;
    v[i] = (t >= 0 && t < Tn) ? y[((size_t)b * Tn + t) * Dn + d] : 0.0f;
  }

  const float bias = dwb[d], w2 = pw2w[0], c2 = pw2b[0];
#pragma unroll
  for (int j = 0; j < 16; ++j) {
    float acc = bias;
#pragma unroll
    for (int k = 0; k < Kw; ++k) acc += w[k] * v[j + k];
    acc = fmaxf(acc, 0.0f);
    const size_t idx = ((size_t)b * Tn + t0 + j) * Dn + d;
    x[idx] = x[idx] + w2 * acc + c2;
  }
}

// ---------------------------------------------------------------------------
extern "C" void kernel_launch(void* const* d_in, const int* in_sizes, int n_in,
                              void* d_out, int out_size, void* d_ws,
                              size_t ws_size, hipStream_t stream) {
  const float* x = (const float*)d_in[0];
  const float* pos_k = (const float*)d_in[1];
  const int* mask = (const int*)d_in[2];
  const float* fi_g = (const float*)d_in[3];
  const float* fi_b = (const float*)d_in[4];
  const float* fi_w1 = (const float*)d_in[5];
  const float* fi_b1 = (const float*)d_in[6];
  const float* fi_w2 = (const float*)d_in[7];
  const float* fi_b2 = (const float*)d_in[8];
  const float* at_g = (const float*)d_in[9];
  const float* at_b = (const float*)d_in[10];
  const float* wq = (const float*)d_in[11];
  const float* bq = (const float*)d_in[12];
  const float* wk = (const float*)d_in[13];
  const float* bk = (const float*)d_in[14];
  const float* wv = (const float*)d_in[15];
  const float* bv = (const float*)d_in[16];
  const float* wo = (const float*)d_in[17];
  const float* bo = (const float*)d_in[18];
  const float* cv_g = (const float*)d_in[19];
  const float* cv_b = (const float*)d_in[20];
  const float* pw1w = (const float*)d_in[21];
  const float* pw1b = (const float*)d_in[22];
  const float* dww = (const float*)d_in[23];
  const float* dwb = (const float*)d_in[24];
  const float* pw2w = (const float*)d_in[25];
  const float* pw2b = (const float*)d_in[26];
  const float* fo_g = (const float*)d_in[27];
  const float* fo_b = (const float*)d_in[28];
  const float* fo_w1 = (const float*)d_in[29];
  const float* fo_b1 = (const float*)d_in[30];
  const float* fo_w2 = (const float*)d_in[31];
  const float* fo_b2 = (const float*)d_in[32];
  const float* fl_g = (const float*)d_in[33];
  const float* fl_b = (const float*)d_in[34];

  float* out = (float*)d_out;

  // ws front: xcur | y | mbits (always)
  float* xcur = (float*)d_ws;
  float* y = xcur + N_OUT;
  uint* mbits = (uint*)(y + N_OUT);  // 512 KB

  // big scratch: prefer ws (enables fused pos_k passthrough); else out region
  const size_t NEED = (size_t)206 << 20;
  const bool fused = ws_size >= NEED;
  char* sp = fused ? (char*)(mbits + N_MASK / 32) : (char*)(out + N_OUT);
  auto alloc16 = [&](size_t elems) {
    ushort* p = (ushort*)sp;
    sp += ((elems * 2 + 255) & ~(size_t)255);
    return p;
  };
  ushort* Sc16 = alloc16((size_t)32 * Tn * Tn);  // 67 MB
  ushort* wt_fi1 = alloc16((size_t)Fn * Dn);
  ushort* wt_fi2 = alloc16((size_t)Dn * Fn);
  ushort* wt_qkv = alloc16((size_t)QS * Dn);  // [1536][512]
  ushort* wt_o = alloc16((size_t)Dn * Dn);
  ushort* wt_fo1 = alloc16((size_t)Fn * Dn);
  ushort* wt_fo2 = alloc16((size_t)Dn * Fn);
  ushort* ybf = alloc16(N_OUT);
  ushort* hbf = alloc16((size_t)Bsz * Tn * Fn);
  ushort* ctxbf = alloc16(N_OUT);
  ushort* qkvbf = alloc16((size_t)Bsz * Tn * QS);  // 25 MB

  const int M = Bsz * Tn;  // 4096
  const dim3 blk256(256);
  const dim3 grid_rows(M);
  const dim3 gF(Fn / 128, M / 128);    // 128x128, N=2048
  const dim3 gD64(Dn / 64, M / 64);    // 64x64,  N=512: 512 blocks
  const dim3 gQKV(QS / 64, M / 128);   // 128x64, N=1536

  // prep: mask passthrough + bit-pack + all weight conversions (one launch)
  prep_kernel<<<dim3(512 + 5120), blk256, 0, stream>>>(
      mask, out + N_OUT + N_POSK, mbits, fi_w1, fi_w2, wq, wk, wv, wo, fo_w1,
      fo_w2, wt_fi1, wt_fi2, wt_qkv, wt_qkv + (size_t)Dn * Dn,
      wt_qkv + (size_t)2 * Dn * Dn, wt_o, wt_fo1, wt_fo2);

  // macaron FFN-in (first LN reads x directly; MODE 1 res=x writes xcur)
  ln_kernel<0, 1><<<grid_rows, blk256, 0, stream>>>(x, fi_g, fi_b, nullptr,
                                                    ybf, nullptr, nullptr);
  mgemm_kernel<0, 128, 128><<<gF, blk256, 0, stream>>>(
      ybf, wt_fi1, fi_b1, nullptr, nullptr, nullptr, nullptr, hbf, M, Fn, Dn);
  mgemm_kernel<1, 64, 64><<<gD64, blk256, 0, stream>>>(
      hbf, wt_fi2, fi_b2, nullptr, nullptr, x, xcur, nullptr, M, Dn, Fn);

  // attention: fused QKV projection (N=1536)
  ln_kernel<0, 1><<<grid_rows, blk256, 0, stream>>>(xcur, at_g, at_b, nullptr,
                                                    ybf, nullptr, nullptr);
  mgemm_kernel<4, 128, 64><<<gQKV, blk256, 0, stream>>>(
      ybf, wt_qkv, bq, bk, bv, nullptr, nullptr, qkvbf, M, QS, Dn);

  if (fused)
    bmm_kernel<1><<<dim3(4, Tn), blk256, 0, stream>>>(qkvbf, pos_k, Sc16,
                                                      out + N_OUT);
  else
    bmm_kernel<0><<<dim3(4, Tn), blk256, 0, stream>>>(qkvbf, pos_k, Sc16,
                                                      nullptr);

  fattn_kernel<<<dim3(Tn / 64, 32), blk256, 0, stream>>>(qkvbf, Sc16, mbits,
                                                         ctxbf);

  mgemm_kernel<3, 64, 64><<<gD64, blk256, 0, stream>>>(
      ctxbf, wt_o, bo, nullptr, nullptr, xcur, xcur, nullptr, M, Dn, Dn);

  // conv module
  ln_kernel<1, 0><<<grid_rows, blk256, 0, stream>>>(xcur, cv_g, cv_b, y,
                                                    nullptr, pw1w, pw1b);
  conv2_kernel<<<dim3(Tn / 16, 2, Bsz), blk256, 0, stream>>>(y, dww, dwb, pw2w,
                                                             pw2b, xcur);

  // macaron FFN-out
  ln_kernel<0, 1><<<grid_rows, blk256, 0, stream>>>(xcur, fo_g, fo_b, nullptr,
                                                    ybf, nullptr, nullptr);
  mgemm_kernel<0, 128, 128><<<gF, blk256, 0, stream>>>(
      ybf, wt_fo1, fo_b1, nullptr, nullptr, nullptr, nullptr, hbf, M, Fn, Dn);
  mgemm_kernel<1, 64, 64><<<gD64, blk256, 0, stream>>>(
      hbf, wt_fo2, fo_b2, nullptr, nullptr, xcur, xcur, nullptr, M, Dn, Fn);

  // final LN -> d_out[0]
  ln_kernel<0, 0><<<grid_rows, blk256, 0, stream>>>(xcur, fl_g, fl_b, out,
                                                    nullptr, nullptr, nullptr);

  // pos_k passthrough (only if not fused into bmm)
  if (!fused)
    hipMemcpyAsync(out + N_OUT, pos_k, N_POSK * sizeof(float),
                   hipMemcpyDeviceToDevice, stream);
}